// Round 3
// baseline (6019.639 us; speedup 1.0000x reference)
//
#include <hip/hip_runtime.h>
#include <hip/hip_bf16.h>

// Problem constants (B,N,H,K from reference)
#define Bd 8
#define Nd 1024
#define Hd 200
#define BN (Bd*Nd)                 // 8192
#define SZ_BNH ((size_t)BN*Hd)     // 1,638,400
#define SZ_BNN ((size_t)BN*Nd)     // 8,388,608

// ---------------- prep ----------------
__global__ void k_prep_masks(const float* __restrict__ tm, float* __restrict__ maskf,
                             float* __restrict__ maskadd){
  int i = blockIdx.x*256 + threadIdx.x;
  if (i < BN){ float m = tm[i]; maskf[i] = m; maskadd[i] = (1.f - m) * -10000.f; }
}

// adj = min(adj1+adj2, 1) -> d_out (fp32); denom[r] = rowsum + 1e-7
__global__ void k_prep_adj(const float* __restrict__ a1, const float* __restrict__ a2,
                           float* __restrict__ adj_out, float* __restrict__ denom){
  int r = blockIdx.x;                 // 0..BN-1 (b*N+n)
  const size_t base = (size_t)r * Nd;
  int t = threadIdx.x;
  float s = 0.f;
  for (int m = t; m < Nd; m += 256){
    float a = a1[base+m] + a2[base+m];
    a = a >= 1.f ? 1.f : a;
    adj_out[base+m] = a;
    s += a;
  }
  __shared__ float red[256];
  red[t] = s; __syncthreads();
  for (int st = 128; st > 0; st >>= 1){ if (t < st) red[t] += red[t+st]; __syncthreads(); }
  if (t == 0) denom[r] = red[0] + 1e-07f;
}

__global__ void k_copy2(const float* __restrict__ x, float* __restrict__ o1,
                        float* __restrict__ o2){
  size_t i = (size_t)blockIdx.x*256 + threadIdx.x;
  if (i < SZ_BNH){ float v = x[i]; o1[i] = v; o2[i] = v; }
}

// ---------------- small GEMM: Y[BN,200] = X[BN,200] @ W[200,200] (+bias) (+gelu) -----
template<int FUSE_GELU>
__global__ void k_gemm_small(const float* __restrict__ X, const float* __restrict__ Wm,
                             const float* __restrict__ bias, float* __restrict__ Y){
  __shared__ float As[16][17], Bs[16][17];
  int ty = threadIdx.y, tx = threadIdx.x;
  int row = blockIdx.y*16 + ty;       // < BN always (BN % 16 == 0)
  int col = blockIdx.x*16 + tx;       // needs < Hd guard
  float acc = 0.f;
  for (int k0 = 0; k0 < Hd; k0 += 16){
    int ka = k0 + tx;
    As[ty][tx] = (ka < Hd) ? X[(size_t)row*Hd + ka] : 0.f;
    int kb = k0 + ty;
    Bs[ty][tx] = (kb < Hd && col < Hd) ? Wm[kb*Hd + col] : 0.f;
    __syncthreads();
    #pragma unroll
    for (int kk = 0; kk < 16; kk++) acc += As[ty][kk] * Bs[kk][tx];
    __syncthreads();
  }
  if (col < Hd){
    float v = acc + (bias ? bias[col] : 0.f);
    if (FUSE_GELU) v = 0.5f * v * (1.f + erff(v * 0.7071067811865476f));
    Y[(size_t)row*Hd + col] = v;
  }
}

// ---------------- NT big: C[b,n,m] = scale*dot(A[b,n,:],B[b,m,:]) + mask epilogue ----
// mode 0: + maskadd[b,m]   (attention scores, key-side mask)
// mode 1: + (1 - maskf[b,n]*maskf[b,m]) * -1e4   (alignment logit)
__global__ void k_nt_big(const float* __restrict__ A, const float* __restrict__ Bm,
                         float* __restrict__ C, float scale,
                         const float* __restrict__ maskadd, const float* __restrict__ maskf,
                         int mode){
  __shared__ float As[16][17], Bs[16][17];
  int b = blockIdx.z, ty = threadIdx.y, tx = threadIdx.x;
  int n = blockIdx.y*16 + ty;
  int m = blockIdx.x*16 + tx;
  const float* Ab = A + (size_t)b*Nd*Hd;
  const float* Bb = Bm + (size_t)b*Nd*Hd;
  float acc = 0.f;
  for (int k0 = 0; k0 < Hd; k0 += 16){
    int k = k0 + tx;
    As[ty][tx] = (k < Hd) ? Ab[(size_t)n*Hd + k] : 0.f;
    Bs[ty][tx] = (k < Hd) ? Bb[(size_t)(blockIdx.x*16 + ty)*Hd + k] : 0.f;
    __syncthreads();
    #pragma unroll
    for (int kk = 0; kk < 16; kk++) acc += As[ty][kk] * Bs[tx][kk];
    __syncthreads();
  }
  int bn = b*Nd + n, bm = b*Nd + m;
  float v;
  if (mode == 0) v = acc*scale + maskadd[bm];
  else           v = acc + (1.f - maskf[bn]*maskf[bm]) * -10000.f;
  C[(size_t)b*Nd*Nd + (size_t)n*Nd + m] = v;
}

// ---------------- NN big: C[b,n,d] = sum_m P(A[b,n,m]) * V[b,m,d], K = 1024 --------
// MODE 0: P = A (already probs);          Y = acc
// MODE 2: P = A (adj);                    Y += relu(acc / denom[b,n])
// MODE 3: P = exp(A - rmax[b,n])/rsum;    Y = acc * maskf[b,n] + R   (on-the-fly row softmax)
template<int MODE>
__global__ void k_nn_big(const float* __restrict__ A, const float* __restrict__ V,
                         float* __restrict__ Y, const float* __restrict__ maskf,
                         const float* __restrict__ denom, const float* __restrict__ R,
                         const float* __restrict__ rmax, const float* __restrict__ rsum){
  __shared__ float As[16][17], Bs[16][17];
  int b = blockIdx.z, ty = threadIdx.y, tx = threadIdx.x;
  int n = blockIdx.y*16 + ty;
  int d = blockIdx.x*16 + tx;
  const float* Ab = A + (size_t)b*Nd*Nd;
  const float* Vb = V + (size_t)b*Nd*Hd;
  float rm = 0.f, ri = 0.f;
  if (MODE == 3){ rm = rmax[b*Nd + n]; ri = 1.f / rsum[b*Nd + n]; }
  float acc = 0.f;
  for (int k0 = 0; k0 < Nd; k0 += 16){
    float av = Ab[(size_t)n*Nd + k0 + tx];
    if (MODE == 3) av = expf(av - rm) * ri;
    As[ty][tx] = av;
    Bs[ty][tx] = (d < Hd) ? Vb[(size_t)(k0+ty)*Hd + d] : 0.f;
    __syncthreads();
    #pragma unroll
    for (int kk = 0; kk < 16; kk++) acc += As[ty][kk] * Bs[kk][tx];
    __syncthreads();
  }
  if (d < Hd){
    size_t idx = (size_t)b*Nd*Hd + (size_t)n*Hd + d;
    if (MODE == 0) Y[idx] = acc;
    else if (MODE == 3) Y[idx] = acc * maskf[b*Nd+n] + R[idx];
    else { float v = acc / denom[b*Nd+n]; v = v > 0.f ? v : 0.f; Y[idx] += v; }
  }
}

// ---------------- TN big with on-the-fly col softmax --------------------------------
// Y[b,m,d] = (sum_n exp(L[b,n,m]-cmax[b,m])/csum[b,m] * X[b,n,d]) * maskf[b,m] + Y
__global__ void k_tn_big(const float* __restrict__ L, const float* __restrict__ X,
                         float* __restrict__ Y, const float* __restrict__ maskf,
                         const float* __restrict__ cmax, const float* __restrict__ csum){
  __shared__ float As[16][17], Bs[16][17];
  int b = blockIdx.z, ty = threadIdx.y, tx = threadIdx.x;
  int m = blockIdx.y*16 + ty;
  int d = blockIdx.x*16 + tx;
  const float* Lb = L + (size_t)b*Nd*Nd;
  const float* Xb = X + (size_t)b*Nd*Hd;
  int mload = blockIdx.y*16 + tx;          // the column this thread loads
  float cm = cmax[b*Nd + mload], ci = 1.f / csum[b*Nd + mload];
  float acc = 0.f;
  for (int k0 = 0; k0 < Nd; k0 += 16){
    As[ty][tx] = expf(Lb[(size_t)(k0+ty)*Nd + mload] - cm) * ci;  // p_col[k][m]
    Bs[ty][tx] = (d < Hd) ? Xb[(size_t)(k0+ty)*Hd + d] : 0.f;     // X[k][d]
    __syncthreads();
    #pragma unroll
    for (int kk = 0; kk < 16; kk++) acc += As[kk][ty] * Bs[kk][tx];
    __syncthreads();
  }
  if (d < Hd){
    size_t idx = (size_t)b*Nd*Hd + (size_t)m*Hd + d;
    Y[idx] = acc * maskf[b*Nd+m] + Y[idx];
  }
}

// ---------------- softmax over last dim (in place), one block per row (attention) ---
__global__ void k_softmax_row(float* __restrict__ S){
  size_t r = blockIdx.x;
  float* row = S + r*Nd;
  int t = threadIdx.x;
  __shared__ float red[256];
  float mx = -3.4e38f;
  for (int i = t; i < Nd; i += 256) mx = fmaxf(mx, row[i]);
  red[t] = mx; __syncthreads();
  for (int s = 128; s > 0; s >>= 1){ if (t < s) red[t] = fmaxf(red[t], red[t+s]); __syncthreads(); }
  mx = red[0]; __syncthreads();
  float sum = 0.f;
  for (int i = t; i < Nd; i += 256){ float e = expf(row[i]-mx); row[i] = e; sum += e; }
  red[t] = sum; __syncthreads();
  for (int s = 128; s > 0; s >>= 1){ if (t < s) red[t] += red[t+s]; __syncthreads(); }
  float inv = 1.f / red[0];
  for (int i = t; i < Nd; i += 256) row[i] *= inv;
}

// ---------------- row stats: rmax[r], rsum[r] = sum exp(row - rmax) -----------------
__global__ void k_rowstats(const float* __restrict__ S, float* __restrict__ rmax,
                           float* __restrict__ rsum){
  size_t r = blockIdx.x;
  const float* row = S + r*Nd;
  int t = threadIdx.x;
  __shared__ float red[256];
  float mx = -3.4e38f;
  for (int i = t; i < Nd; i += 256) mx = fmaxf(mx, row[i]);
  red[t] = mx; __syncthreads();
  for (int s = 128; s > 0; s >>= 1){ if (t < s) red[t] = fmaxf(red[t], red[t+s]); __syncthreads(); }
  mx = red[0]; __syncthreads();
  float sum = 0.f;
  for (int i = t; i < Nd; i += 256) sum += expf(row[i]-mx);
  red[t] = sum; __syncthreads();
  for (int s = 128; s > 0; s >>= 1){ if (t < s) red[t] += red[t+s]; __syncthreads(); }
  if (t == 0){ rmax[r] = mx; rsum[r] = red[0]; }
}

// ---------------- col stats: cmax[b,m], csum[b,m] -----------------------------------
// grid (Nd/64, Bd); 256 threads = 64 cols x 4 row-strides
__global__ void k_colstats(const float* __restrict__ S, float* __restrict__ cmax,
                           float* __restrict__ csum){
  int b = blockIdx.y;
  int tx = threadIdx.x & 63;
  int ty = threadIdx.x >> 6;
  int m = blockIdx.x*64 + tx;
  const float* Sb = S + (size_t)b*Nd*Nd;
  __shared__ float red[256];
  float mx = -3.4e38f;
  for (int n = ty; n < Nd; n += 4) mx = fmaxf(mx, Sb[(size_t)n*Nd + m]);
  red[threadIdx.x] = mx; __syncthreads();
  if (ty == 0) red[tx] = fmaxf(fmaxf(red[tx], red[64+tx]), fmaxf(red[128+tx], red[192+tx]));
  __syncthreads();
  mx = red[tx]; __syncthreads();
  float s = 0.f;
  for (int n = ty; n < Nd; n += 4) s += expf(Sb[(size_t)n*Nd + m] - mx);
  red[threadIdx.x] = s; __syncthreads();
  if (ty == 0){
    float tot = red[tx] + red[64+tx] + red[128+tx] + red[192+tx];
    cmax[b*Nd + m] = mx; csum[b*Nd + m] = tot;
  }
}

// ---------------- residual + layernorm: Y = LN(X + R; g, b), one block per row ------
// In-place safe for Y==X (each block touches only its own row).
__global__ void k_add_ln(const float* __restrict__ X, const float* __restrict__ R,
                         const float* __restrict__ g, const float* __restrict__ bb,
                         float* __restrict__ Y){
  int r = blockIdx.x, t = threadIdx.x;
  __shared__ float red[256];
  bool act = t < Hd;
  float v = 0.f;
  if (act) v = X[(size_t)r*Hd + t] + R[(size_t)r*Hd + t];
  red[t] = act ? v : 0.f; __syncthreads();
  for (int s = 128; s > 0; s >>= 1){ if (t < s) red[t] += red[t+s]; __syncthreads(); }
  float mu = red[0] * (1.f/Hd); __syncthreads();
  float d = act ? (v - mu) : 0.f;
  red[t] = d*d; __syncthreads();
  for (int s = 128; s > 0; s >>= 1){ if (t < s) red[t] += red[t+s]; __syncthreads(); }
  float var = red[0] * (1.f/Hd);
  if (act){
    float rs = 1.f / sqrtf(var + 1e-20f);
    Y[(size_t)r*Hd + t] = (v - mu) * rs * g[t] + bb[t];
  }
}

__global__ void k_store(const float* __restrict__ X, float* __restrict__ O){
  size_t i = (size_t)blockIdx.x*256 + threadIdx.x;
  if (i < SZ_BNH) O[i] = X[i];
}

extern "C" void kernel_launch(void* const* d_in, const int* in_sizes, int n_in,
                              void* d_out, int out_size, void* d_ws, size_t ws_size,
                              hipStream_t stream){
  (void)in_sizes; (void)n_in; (void)out_size; (void)ws_size;
  const float* text     = (const float*)d_in[0];
  const float* adj1     = (const float*)d_in[1];
  const float* adj2     = (const float*)d_in[2];
  // d_in[3], d_in[4] (edge1/edge2 int32) unused by reference forward
  const float* textmask = (const float*)d_in[5];
  const float* gcn_w    = (const float*)d_in[6];
  const float* mut_w    = (const float*)d_in[7];
  const float* qw = (const float*)d_in[8],  *qb = (const float*)d_in[9];
  const float* kw = (const float*)d_in[10], *kb = (const float*)d_in[11];
  const float* vw = (const float*)d_in[12], *vb = (const float*)d_in[13];
  const float* aow= (const float*)d_in[14], *aob= (const float*)d_in[15];
  const float* g1 = (const float*)d_in[16], *b1 = (const float*)d_in[17];
  const float* iw = (const float*)d_in[18], *ib = (const float*)d_in[19];
  const float* ow = (const float*)d_in[20], *ob = (const float*)d_in[21];
  const float* g2 = (const float*)d_in[22], *b2 = (const float*)d_in[23];

  float* out_outs = (float*)d_out;
  float* out_adj  = out_outs + SZ_BNH;

  // workspace layout: 4*BNH + BNN + 7*BN floats = ~60.0 MB
  float* w = (float*)d_ws;
  float* bufA    = w; w += SZ_BNH;   // "outs" ping
  float* t_a     = w; w += SZ_BNH;   // scratch / "outs" pong
  float* t_b     = w; w += SZ_BNH;   // scratch
  float* f_output= w; w += SZ_BNH;   // "output"
  float* S       = w; w += SZ_BNN;   // scores / logits
  float* denom   = w; w += BN;
  float* maskf   = w; w += BN;
  float* maskadd = w; w += BN;
  float* rmaxv   = w; w += BN;
  float* rsumv   = w; w += BN;
  float* cmaxv   = w; w += BN;
  float* csumv   = w; w += BN;

  dim3 blk2(16,16);
  dim3 grid_small((Hd+15)/16, BN/16);        // 13 x 512
  dim3 grid_nt(Nd/16, Nd/16, Bd);            // 64 x 64 x 8
  dim3 grid_nn((Hd+15)/16, Nd/16, Bd);       // 13 x 64 x 8

  k_prep_masks<<<(BN+255)/256, 256, 0, stream>>>(textmask, maskf, maskadd);
  k_prep_adj<<<BN, 256, 0, stream>>>(adj1, adj2, out_adj, denom);
  k_copy2<<<(int)((SZ_BNH+255)/256), 256, 0, stream>>>(text, bufA, f_output);

  float* cur = bufA;     // "outs"
  float* alt = t_a;      // becomes next "outs" (swapped each layer)
  const float inv_sqrt_h = 0.07071067811865475f;  // 1/sqrt(200)

  for (int i = 0; i < 3; i++){
    const float *qwi = qw + i*Hd*Hd, *qbi = qb + i*Hd;
    const float *kwi = kw + i*Hd*Hd, *kbi = kb + i*Hd;
    const float *vwi = vw + i*Hd*Hd, *vbi = vb + i*Hd;
    const float *aowi= aow+ i*Hd*Hd, *aobi= aob+ i*Hd;
    const float *g1i = g1 + i*Hd,    *b1i = b1 + i*Hd;
    const float *iwi = iw + i*Hd*Hd, *ibi = ib + i*Hd;
    const float *owi = ow + i*Hd*Hd, *obi = ob + i*Hd;
    const float *g2i = g2 + i*Hd,    *b2i = b2 + i*Hd;

    // ---- BERT layer: cur -> cur (uses alt, t_b as scratch) ----
    k_gemm_small<0><<<grid_small, blk2, 0, stream>>>(cur, qwi, qbi, alt);     // Q
    k_gemm_small<0><<<grid_small, blk2, 0, stream>>>(cur, kwi, kbi, t_b);     // K
    k_nt_big<<<grid_nt, blk2, 0, stream>>>(alt, t_b, S, inv_sqrt_h, maskadd, maskf, 0);
    k_gemm_small<0><<<grid_small, blk2, 0, stream>>>(cur, vwi, vbi, alt);     // V (Q dead)
    k_softmax_row<<<BN, 256, 0, stream>>>(S);
    k_nn_big<0><<<grid_nn, blk2, 0, stream>>>(S, alt, t_b,                    // ctx (K dead)
                                              nullptr, nullptr, nullptr, nullptr, nullptr);
    k_gemm_small<0><<<grid_small, blk2, 0, stream>>>(t_b, aowi, aobi, alt);   // ao_out (V dead)
    k_add_ln<<<BN, 256, 0, stream>>>(alt, cur, g1i, b1i, t_b);                // attn (ctx dead)
    k_gemm_small<1><<<grid_small, blk2, 0, stream>>>(t_b, iwi, ibi, alt);     // gelu(inter)
    k_gemm_small<0><<<grid_small, blk2, 0, stream>>>(alt, owi, obi, cur);     // ow_out (old outs dead)
    k_add_ln<<<BN, 256, 0, stream>>>(cur, t_b, g2i, b2i, cur);                // bert out, in place

    // ---- GCN on f_output ----
    k_gemm_small<0><<<grid_small, blk2, 0, stream>>>(f_output, gcn_w, nullptr, alt);  // teout
    k_nn_big<2><<<grid_nn, blk2, 0, stream>>>(out_adj, alt, f_output,
                                              nullptr, denom, nullptr, nullptr, nullptr);

    // ---- self-alignment ----
    k_gemm_small<0><<<grid_small, blk2, 0, stream>>>(cur, mut_w, nullptr, alt);       // mm
    k_nt_big<<<grid_nt, blk2, 0, stream>>>(alt, f_output, S, 1.f, maskadd, maskf, 1); // logits
    k_colstats<<<dim3(Nd/64, Bd), 256, 0, stream>>>(S, cmaxv, csumv);
    k_rowstats<<<BN, 256, 0, stream>>>(S, rmaxv, rsumv);
    // new_outs = (p_row @ output) * mask_n + outs  -> alt (mm dead; reads OLD cur, NEW f_output)
    k_nn_big<3><<<grid_nn, blk2, 0, stream>>>(S, f_output, alt,
                                              maskf, nullptr, cur, rmaxv, rsumv);
    // output = (p_col^T @ outs) * mask_m + output  (in place; reads OLD cur)
    k_tn_big<<<grid_nn, blk2, 0, stream>>>(S, cur, f_output, maskf, cmaxv, csumv);

    float* t = cur; cur = alt; alt = t;   // outs = new_outs
  }

  k_store<<<(int)((SZ_BNH+255)/256), 256, 0, stream>>>(cur, out_outs);
}

// Round 6
// 2969.136 us; speedup vs baseline: 2.0274x; 2.0274x over previous
//
#include <hip/hip_runtime.h>
#include <hip/hip_bf16.h>
#include <math.h>

// Problem constants
#define Bd 8
#define Nd 1024
#define Hd 200
#define HP 224                      // Hd padded to multiple of 32
#define BN (Bd*Nd)                  // 8192
#define SZ_BNH ((size_t)BN*Hd)      // 1,638,400
#define SZ_BNN ((size_t)BN*Nd)      // 8,388,608
#define SZ_PAD ((size_t)BN*HP)      // 1,835,008

typedef __hip_bfloat16 bf16;
typedef __attribute__((ext_vector_type(8))) short bf16x8;   // 8 bf16 = 4 VGPRs (A/B frag)
typedef __attribute__((ext_vector_type(4))) float f32x4;    // C/D frag

__device__ __forceinline__ float bf2f(bf16 v){ return __bfloat162float(v); }
__device__ __forceinline__ bf16 f2bf(float v){ return __float2bfloat16(v); }

// ============================ prep (fp32) ============================
__global__ void k_prep_masks(const float* __restrict__ tm, float* __restrict__ maskf,
                             float* __restrict__ maskadd){
  int i = blockIdx.x*256 + threadIdx.x;
  if (i < BN){ float m = tm[i]; maskf[i] = m; maskadd[i] = (1.f - m) * -10000.f; }
}

__global__ void k_prep_adj(const float* __restrict__ a1, const float* __restrict__ a2,
                           float* __restrict__ adj_out, float* __restrict__ denom){
  int r = blockIdx.x;
  const size_t base = (size_t)r * Nd;
  int t = threadIdx.x;
  float s = 0.f;
  for (int m = t; m < Nd; m += 256){
    float a = a1[base+m] + a2[base+m];
    a = a >= 1.f ? 1.f : a;
    adj_out[base+m] = a;
    s += a;
  }
  __shared__ float red[256];
  red[t] = s; __syncthreads();
  for (int st = 128; st > 0; st >>= 1){ if (t < st) red[t] += red[t+st]; __syncthreads(); }
  if (t == 0) denom[r] = red[0] + 1e-07f;
}

__global__ void k_copy2(const float* __restrict__ x, float* __restrict__ o1,
                        float* __restrict__ o2){
  size_t i = (size_t)blockIdx.x*256 + threadIdx.x;
  if (i < SZ_BNH){ float v = x[i]; o1[i] = v; o2[i] = v; }
}

// ============================ split conversions ============================
// fp32 [BN][200] -> bf16 hi/lo [BN][224] zero-padded
__global__ void c_pad_split(const float* __restrict__ X, bf16* __restrict__ Oh,
                            bf16* __restrict__ Ol){
  size_t i = (size_t)blockIdx.x*256 + threadIdx.x;
  if (i >= SZ_PAD) return;
  int c = (int)(i % HP); size_t r = i / HP;
  float v = (c < Hd) ? X[r*Hd + c] : 0.f;
  bf16 h = f2bf(v);
  Oh[i] = h; Ol[i] = f2bf(v - bf2f(h));
}

// fp32 [b][1024][200] -> bf16 hi/lo [b][224][1024] transposed, zero-padded
__global__ void c_padT_split(const float* __restrict__ X, bf16* __restrict__ Oh,
                             bf16* __restrict__ Ol){
  __shared__ float t[32][33];
  int b = blockIdx.z, m0 = blockIdx.x*32, d0 = blockIdx.y*32;
  int tx = threadIdx.x, ty = threadIdx.y;          // block (32,8)
  for (int i = ty; i < 32; i += 8){
    int d = d0 + tx;
    t[i][tx] = (d < Hd) ? X[((size_t)b*Nd + m0+i)*Hd + d] : 0.f;
  }
  __syncthreads();
  for (int i = ty; i < 32; i += 8){
    size_t idx = (size_t)b*HP*Nd + (size_t)(d0+i)*Nd + m0 + tx;
    float v = t[tx][i];
    bf16 h = f2bf(v);
    Oh[idx] = h; Ol[idx] = f2bf(v - bf2f(h));
  }
}

// W fp32 [200][200] -> bf16 hi/lo [224][224]: O[n][k] = W[k][n], zero-padded
__global__ void c_w_split(const float* __restrict__ W, bf16* __restrict__ Oh,
                          bf16* __restrict__ Ol){
  int i = blockIdx.x*256 + threadIdx.x;
  if (i >= HP*HP) return;
  int n = i / HP, k = i % HP;
  float v = (n < Hd && k < Hd) ? W[k*Hd + n] : 0.f;
  bf16 h = f2bf(v);
  Oh[i] = h; Ol[i] = f2bf(v - bf2f(h));
}

// fp32 [B][1024][1024] -> bf16 same layout (adj: exact 0/1 values)
__global__ void c_cvt1024(const float* __restrict__ X, bf16* __restrict__ O){
  size_t i = (size_t)blockIdx.x*256 + threadIdx.x;
  if (i < SZ_BNN) O[i] = f2bf(X[i]);
}

// attention probs: single bf16 (LN-protected downstream)
__global__ void c_prow(const float* __restrict__ S, const float* __restrict__ rmax,
                       const float* __restrict__ rsum, bf16* __restrict__ P){
  size_t i = (size_t)blockIdx.x*256 + threadIdx.x;
  if (i >= SZ_BNN) return;
  size_t r = i >> 10;
  P[i] = f2bf(expf(S[i] - rmax[r]) * (1.f / rsum[r]));
}

// alignment p_row: split pair
__global__ void c_prow_split(const float* __restrict__ S, const float* __restrict__ rmax,
                             const float* __restrict__ rsum, bf16* __restrict__ Ph,
                             bf16* __restrict__ Pl){
  size_t i = (size_t)blockIdx.x*256 + threadIdx.x;
  if (i >= SZ_BNN) return;
  size_t r = i >> 10;
  float p = expf(S[i] - rmax[r]) * (1.f / rsum[r]);
  bf16 h = f2bf(p);
  Ph[i] = h; Pl[i] = f2bf(p - bf2f(h));
}

// alignment p_col^T: split pair, transposed
__global__ void c_pcolT_split(const float* __restrict__ S, const float* __restrict__ cmax,
                              const float* __restrict__ csum, bf16* __restrict__ Ph,
                              bf16* __restrict__ Pl){
  __shared__ float t[32][33];
  int b = blockIdx.z, n0 = blockIdx.x*32, m0 = blockIdx.y*32;
  int tx = threadIdx.x, ty = threadIdx.y;          // block (32,8)
  for (int i = ty; i < 32; i += 8)
    t[i][tx] = S[(size_t)b*Nd*Nd + (size_t)(n0+i)*Nd + m0 + tx];
  __syncthreads();
  for (int i = ty; i < 32; i += 8){
    int m = m0 + i;
    float cm = cmax[b*Nd + m], ci = 1.f / csum[b*Nd + m];
    float p = expf(t[tx][i] - cm) * ci;
    size_t idx = (size_t)b*Nd*Nd + (size_t)m*Nd + n0 + tx;
    bf16 h = f2bf(p);
    Ph[idx] = h; Pl[idx] = f2bf(p - bf2f(h));
  }
}

// ============================ softmax stats (fp32) ============================
__global__ void k_rowstats(const float* __restrict__ S, float* __restrict__ rmax,
                           float* __restrict__ rsum){
  size_t r = blockIdx.x;
  const float* row = S + r*Nd;
  int t = threadIdx.x;
  __shared__ float red[256];
  float mx = -3.4e38f;
  for (int i = t; i < Nd; i += 256) mx = fmaxf(mx, row[i]);
  red[t] = mx; __syncthreads();
  for (int s = 128; s > 0; s >>= 1){ if (t < s) red[t] = fmaxf(red[t], red[t+s]); __syncthreads(); }
  mx = red[0]; __syncthreads();
  float sum = 0.f;
  for (int i = t; i < Nd; i += 256) sum += expf(row[i] - mx);
  red[t] = sum; __syncthreads();
  for (int s = 128; s > 0; s >>= 1){ if (t < s) red[t] += red[t+s]; __syncthreads(); }
  if (t == 0){ rmax[r] = mx; rsum[r] = red[0]; }
}

__global__ void k_colstats(const float* __restrict__ S, float* __restrict__ cmax,
                           float* __restrict__ csum){
  int b = blockIdx.y;
  int tx = threadIdx.x & 63, ty = threadIdx.x >> 6;
  int m = blockIdx.x*64 + tx;
  const float* Sbp = S + (size_t)b*Nd*Nd;
  __shared__ float red[256];
  float mx = -3.4e38f;
  for (int n = ty; n < Nd; n += 4) mx = fmaxf(mx, Sbp[(size_t)n*Nd + m]);
  red[threadIdx.x] = mx; __syncthreads();
  if (ty == 0) red[tx] = fmaxf(fmaxf(red[tx], red[64+tx]), fmaxf(red[128+tx], red[192+tx]));
  __syncthreads();
  mx = red[tx]; __syncthreads();
  float s = 0.f;
  for (int n = ty; n < Nd; n += 4) s += expf(Sbp[(size_t)n*Nd + m] - mx);
  red[threadIdx.x] = s; __syncthreads();
  if (ty == 0){
    float tot = red[tx] + red[64+tx] + red[128+tx] + red[192+tx];
    cmax[b*Nd + m] = mx; csum[b*Nd + m] = tot;
  }
}

// ============================ residual + layernorm ============================
__global__ void k_add_ln(const float* __restrict__ X, const float* __restrict__ R,
                         const float* __restrict__ g, const float* __restrict__ bb,
                         float* __restrict__ Y){
  int r = blockIdx.x, t = threadIdx.x;
  __shared__ float red[256];
  bool act = t < Hd;
  float v = 0.f;
  if (act) v = X[(size_t)r*Hd + t] + R[(size_t)r*Hd + t];
  red[t] = act ? v : 0.f; __syncthreads();
  for (int s = 128; s > 0; s >>= 1){ if (t < s) red[t] += red[t+s]; __syncthreads(); }
  float mu = red[0] * (1.f/Hd); __syncthreads();
  float d = act ? (v - mu) : 0.f;
  red[t] = d*d; __syncthreads();
  for (int s = 128; s > 0; s >>= 1){ if (t < s) red[t] += red[t+s]; __syncthreads(); }
  float var = red[0] * (1.f/Hd);
  if (act){
    float rs = 1.f / sqrtf(var + 1e-20f);
    Y[(size_t)r*Hd + t] = (v - mu) * rs * g[t] + bb[t];
  }
}

__global__ void k_store(const float* __restrict__ X, float* __restrict__ O){
  size_t i = (size_t)blockIdx.x*256 + threadIdx.x;
  if (i < SZ_BNH) O[i] = X[i];
}

// ============================ split-precision MFMA GEMM ============================
// D[m][n] = sum_k A[m][k]*B[n][k] (NT) with A = Ah+Al, B = Bh+Bl (Dekker split).
// TERMS=3: Ah*Bh + Ah*Bl + Al*Bh (drops Al*Bl ~2^-18). TERMS=2: Ah*(Bh+Bl), A exact.
// 16x16x32 bf16, 1 wave per C tile. Frag: [idx=lane&15][k=(lane>>4)*8+j];
// C/D: col=lane&15, row=(lane>>4)*4+reg.
// EPI: 0 fp32 Y=acc+bias  1 +gelu  2 split-bf16pad out (Ybh/Ybl)
//      3 S=acc*scale+maskadd[col]  4 S=acc+pairmask  5 Y+=relu(acc/denom[row])
//      6 Y=acc*maskf[row]+R  7 Y=acc*maskf[row]+Y
template<int EPI, int TERMS>
__global__ __launch_bounds__(256)
void k_mfma3(const bf16* __restrict__ Ah, const bf16* __restrict__ Al,
             const bf16* __restrict__ Bh, const bf16* __restrict__ Bl,
             float* __restrict__ Y, bf16* __restrict__ Ybh, bf16* __restrict__ Ybl,
             const float* __restrict__ bias, const float* __restrict__ e0,
             const float* __restrict__ e1, const float* __restrict__ R,
             int Kp, size_t sAb, size_t sBb, float scale)
{
  int b = blockIdx.z;
  int wave = threadIdx.x >> 6, lane = threadIdx.x & 63;
  int m0 = (blockIdx.y*4 + wave)*16;
  int n0 = blockIdx.x*16;
  int lm = lane & 15, lq = lane >> 4;
  size_t aoff = (size_t)b*sAb + (size_t)(m0+lm)*Kp + lq*8;
  size_t boff = (size_t)b*sBb + (size_t)(n0+lm)*Kp + lq*8;
  const bf16* pAh = Ah + aoff;
  const bf16* pBh = Bh + boff;
  const bf16* pBl = Bl + boff;
  const bf16* pAl = (TERMS >= 3) ? (Al + aoff) : nullptr;
  f32x4 acc = {0.f,0.f,0.f,0.f};
  for (int k = 0; k < Kp; k += 32){
    bf16x8 ah = *(const bf16x8*)(pAh + k);
    bf16x8 bh = *(const bf16x8*)(pBh + k);
    bf16x8 bl = *(const bf16x8*)(pBl + k);
    acc = __builtin_amdgcn_mfma_f32_16x16x32_bf16(ah, bh, acc, 0, 0, 0);
    acc = __builtin_amdgcn_mfma_f32_16x16x32_bf16(ah, bl, acc, 0, 0, 0);
    if (TERMS >= 3){
      bf16x8 al = *(const bf16x8*)(pAl + k);
      acc = __builtin_amdgcn_mfma_f32_16x16x32_bf16(al, bh, acc, 0, 0, 0);
    }
  }
  int col = n0 + lm;
  int rbase = m0 + lq*4;
  #pragma unroll
  for (int r = 0; r < 4; r++){
    int row = rbase + r;
    size_t rowg = (size_t)b*Nd + row;
    float v = acc[r];
    if (EPI == 0 || EPI == 1){
      if (col < Hd){
        v += bias ? bias[col] : 0.f;
        if (EPI == 1) v = 0.5f*v*(1.f + erff(v*0.7071067811865476f));
        Y[rowg*Hd + col] = v;
      }
    } else if (EPI == 2){
      float o = (col < Hd) ? v + (bias ? bias[col] : 0.f) : 0.f;
      bf16 h = f2bf(o);
      Ybh[rowg*HP + col] = h;
      Ybl[rowg*HP + col] = f2bf(o - bf2f(h));
    } else if (EPI == 3){
      Y[rowg*Nd + col] = v*scale + e0[b*Nd + col];
    } else if (EPI == 4){
      Y[rowg*Nd + col] = v + (1.f - e1[b*Nd+row]*e1[b*Nd+col])*(-10000.f);
    } else if (EPI == 5){
      if (col < Hd){
        float u = v / e0[b*Nd+row]; u = u > 0.f ? u : 0.f;
        Y[rowg*Hd + col] += u;
      }
    } else if (EPI == 6){
      if (col < Hd) Y[rowg*Hd+col] = v*e1[b*Nd+row] + R[rowg*Hd+col];
    } else if (EPI == 7){
      if (col < Hd) Y[rowg*Hd+col] = v*e1[b*Nd+row] + Y[rowg*Hd+col];
    }
  }
}

// ============================ host launch ============================
static inline char* carve(char*& p, size_t bytes){
  char* r = p;
  p += (bytes + 511) & ~(size_t)511;
  return r;
}

extern "C" void kernel_launch(void* const* d_in, const int* in_sizes, int n_in,
                              void* d_out, int out_size, void* d_ws, size_t ws_size,
                              hipStream_t stream){
  (void)in_sizes; (void)n_in; (void)out_size; (void)ws_size;
  const float* text     = (const float*)d_in[0];
  const float* adj1     = (const float*)d_in[1];
  const float* adj2     = (const float*)d_in[2];
  const float* textmask = (const float*)d_in[5];
  const float* gcn_w    = (const float*)d_in[6];
  const float* mut_w    = (const float*)d_in[7];
  const float* qw = (const float*)d_in[8],  *qb = (const float*)d_in[9];
  const float* kw = (const float*)d_in[10], *kb = (const float*)d_in[11];
  const float* vw = (const float*)d_in[12], *vb = (const float*)d_in[13];
  const float* aow= (const float*)d_in[14], *aob= (const float*)d_in[15];
  const float* g1 = (const float*)d_in[16], *b1 = (const float*)d_in[17];
  const float* iw = (const float*)d_in[18], *ib = (const float*)d_in[19];
  const float* ow = (const float*)d_in[20], *ob = (const float*)d_in[21];
  const float* g2 = (const float*)d_in[22], *b2 = (const float*)d_in[23];

  float* out_outs = (float*)d_out;
  float* out_adj  = out_outs + SZ_BNH;

  // ---- workspace carve (~109 MB). out_outs doubles as fp32 scratch sc2. ----
  char* p = (char*)d_ws;
  float* cur  = (float*)carve(p, SZ_BNH*4);
  float* sc1  = (float*)carve(p, SZ_BNH*4);
  float* fo   = (float*)carve(p, SZ_BNH*4);
  float* S    = (float*)carve(p, SZ_BNN*4);           // fp32 scores / logits
  bf16*  Rb   = (bf16*)carve(p, SZ_BNN*2*2);          // big bf16 region (33.6 MB)
  bf16*  T1   = (bf16*)carve(p, SZ_PAD*2);
  bf16*  T2   = (bf16*)carve(p, SZ_PAD*2);
  bf16*  T3   = (bf16*)carve(p, SZ_PAD*2);
  bf16*  T4   = (bf16*)carve(p, SZ_PAD*2);
  bf16*  T5   = (bf16*)carve(p, SZ_PAD*2);
  bf16*  T6   = (bf16*)carve(p, SZ_PAD*2);
  bf16*  Wh   = (bf16*)carve(p, (size_t)HP*HP*2);
  bf16*  Wl   = (bf16*)carve(p, (size_t)HP*HP*2);
  float* denom   = (float*)carve(p, BN*4);
  float* maskf   = (float*)carve(p, BN*4);
  float* maskadd = (float*)carve(p, BN*4);
  float* rmaxv   = (float*)carve(p, BN*4);
  float* rsumv   = (float*)carve(p, BN*4);
  float* cmaxv   = (float*)carve(p, BN*4);
  float* csumv   = (float*)carve(p, BN*4);

  float* sc2 = out_outs;          // fp32 scratch; overwritten by final k_store
  bf16* attnP = Rb;               // phases: attnP -> adjb -> Ph/Pl (sequential)
  bf16* adjb  = Rb;
  bf16* Ph    = Rb;
  bf16* Pl    = Rb + SZ_BNN;

  const size_t sNT = (size_t)Nd*HP;     // batch stride, [1024][224]
  const size_t sT  = (size_t)HP*Nd;     // batch stride, [224][1024]
  const size_t sNN = (size_t)Nd*Nd;     // batch stride, [1024][1024]

  dim3 blk256(256);
  dim3 gPad((unsigned)((SZ_PAD+255)/256));
  dim3 gPadT(32, 7, Bd), bT(32, 8);
  dim3 gPcolT(32, 32, Bd);
  dim3 gW((HP*HP+255)/256);
  dim3 gNNel((unsigned)((SZ_BNN+255)/256));
  dim3 gBNH((unsigned)((SZ_BNH+255)/256));
  dim3 gSm200(13, 128, 1);   // small GEMM, fp32 200-wide out
  dim3 gSm224(14, 128, 1);   // small GEMM, split-bf16 224-wide out
  dim3 gNT(64, 16, Bd);      // [1024x1024] out, K=HP
  dim3 gBig200(13, 16, Bd);  // K=1024, 200-wide out
  const float inv_sqrt_h = 0.07071067811865475f;  // 1/sqrt(200)
  const size_t Z = 0;

  k_prep_masks<<<(BN+255)/256, blk256, 0, stream>>>(textmask, maskf, maskadd);
  k_prep_adj<<<BN, blk256, 0, stream>>>(adj1, adj2, out_adj, denom);
  k_copy2<<<gBNH, blk256, 0, stream>>>(text, cur, fo);

  for (int i = 0; i < 3; i++){
    const float *qwi = qw + i*Hd*Hd, *qbi = qb + i*Hd;
    const float *kwi = kw + i*Hd*Hd, *kbi = kb + i*Hd;
    const float *vwi = vw + i*Hd*Hd, *vbi = vb + i*Hd;
    const float *aowi= aow+ i*Hd*Hd, *aobi= aob+ i*Hd;
    const float *g1i = g1 + i*Hd,    *b1i = b1 + i*Hd;
    const float *iwi = iw + i*Hd*Hd, *ibi = ib + i*Hd;
    const float *owi = ow + i*Hd*Hd, *obi = ob + i*Hd;
    const float *g2i = g2 + i*Hd,    *b2i = b2 + i*Hd;

    // ================= BERT layer: cur -> cur =================
    c_pad_split<<<gPad, blk256, 0, stream>>>(cur, T1, T2);                  // cur pair
    c_w_split<<<gW, blk256, 0, stream>>>(qwi, Wh, Wl);
    k_mfma3<2,3><<<gSm224, blk256, 0, stream>>>(T1,T2,Wh,Wl, nullptr,T3,T4,
              qbi, nullptr,nullptr,nullptr, HP, Z,Z, 0.f);                  // Q pair
    c_w_split<<<gW, blk256, 0, stream>>>(kwi, Wh, Wl);
    k_mfma3<2,3><<<gSm224, blk256, 0, stream>>>(T1,T2,Wh,Wl, nullptr,T5,T6,
              kbi, nullptr,nullptr,nullptr, HP, Z,Z, 0.f);                  // K pair
    k_mfma3<3,3><<<gNT, blk256, 0, stream>>>(T3,T4,T5,T6, S,nullptr,nullptr,
              nullptr, maskadd,nullptr,nullptr, HP, sNT,sNT, inv_sqrt_h);   // scores
    c_w_split<<<gW, blk256, 0, stream>>>(vwi, Wh, Wl);
    k_mfma3<0,3><<<gSm200, blk256, 0, stream>>>(T1,T2,Wh,Wl, sc1,nullptr,nullptr,
              vbi, nullptr,nullptr,nullptr, HP, Z,Z, 0.f);                  // V fp32
    k_rowstats<<<BN, blk256, 0, stream>>>(S, rmaxv, rsumv);
    c_prow<<<gNNel, blk256, 0, stream>>>(S, rmaxv, rsumv, attnP);           // probs (single)
    c_padT_split<<<gPadT, bT, 0, stream>>>(sc1, T1, T2);                    // V^T pair
    k_mfma3<0,2><<<gBig200, blk256, 0, stream>>>(attnP,nullptr,T1,T2,
              sc2,nullptr,nullptr, nullptr, nullptr,nullptr,nullptr,
              Nd, sNN,sT, 0.f);                                             // ctx
    c_pad_split<<<gPad, blk256, 0, stream>>>(sc2, T3, T4);
    c_w_split<<<gW, blk256, 0, stream>>>(aowi, Wh, Wl);
    k_mfma3<0,3><<<gSm200, blk256, 0, stream>>>(T3,T4,Wh,Wl, sc1,nullptr,nullptr,
              aobi, nullptr,nullptr,nullptr, HP, Z,Z, 0.f);                 // ao_out
    k_add_ln<<<BN, blk256, 0, stream>>>(sc1, cur, g1i, b1i, sc2);           // attn -> sc2
    c_pad_split<<<gPad, blk256, 0, stream>>>(sc2, T1, T2);
    c_w_split<<<gW, blk256, 0, stream>>>(iwi, Wh, Wl);
    k_mfma3<1,3><<<gSm200, blk256, 0, stream>>>(T1,T2,Wh,Wl, sc1,nullptr,nullptr,
              ibi, nullptr,nullptr,nullptr, HP, Z,Z, 0.f);                  // gelu(inter)
    c_pad_split<<<gPad, blk256, 0, stream>>>(sc1, T3, T4);
    c_w_split<<<gW, blk256, 0, stream>>>(owi, Wh, Wl);
    k_mfma3<0,3><<<gSm200, blk256, 0, stream>>>(T3,T4,Wh,Wl, cur,nullptr,nullptr,
              obi, nullptr,nullptr,nullptr, HP, Z,Z, 0.f);                  // ow_out -> cur
    k_add_ln<<<BN, blk256, 0, stream>>>(cur, sc2, g2i, b2i, cur);           // bert out

    // ================= GCN on fo =================
    c_pad_split<<<gPad, blk256, 0, stream>>>(fo, T1, T2);
    c_w_split<<<gW, blk256, 0, stream>>>(gcn_w, Wh, Wl);
    k_mfma3<0,3><<<gSm200, blk256, 0, stream>>>(T1,T2,Wh,Wl, sc1,nullptr,nullptr,
              nullptr, nullptr,nullptr,nullptr, HP, Z,Z, 0.f);              // teout
    c_padT_split<<<gPadT, bT, 0, stream>>>(sc1, T3, T4);                    // teout^T pair
    c_cvt1024<<<gNNel, blk256, 0, stream>>>(out_adj, adjb);                 // adj bf16 exact
    k_mfma3<5,2><<<gBig200, blk256, 0, stream>>>(adjb,nullptr,T3,T4,
              fo,nullptr,nullptr, nullptr, denom,nullptr,nullptr,
              Nd, sNN,sT, 0.f);                                             // fo += relu(./denom)

    // ================= self-alignment =================
    c_pad_split<<<gPad, blk256, 0, stream>>>(cur, T1, T2);
    c_w_split<<<gW, blk256, 0, stream>>>(mut_w, Wh, Wl);
    k_mfma3<2,3><<<gSm224, blk256, 0, stream>>>(T1,T2,Wh,Wl, nullptr,T5,T6,
              nullptr, nullptr,nullptr,nullptr, HP, Z,Z, 0.f);              // mm pair
    c_pad_split<<<gPad, blk256, 0, stream>>>(fo, T1, T2);                   // fo pad pair
    k_mfma3<4,3><<<gNT, blk256, 0, stream>>>(T5,T6,T1,T2, S,nullptr,nullptr,
              nullptr, nullptr,maskf,nullptr, HP, sNT,sNT, 0.f);            // logits -> S
    k_colstats<<<dim3(Nd/64, Bd), blk256, 0, stream>>>(S, cmaxv, csumv);
    k_rowstats<<<BN, blk256, 0, stream>>>(S, rmaxv, rsumv);
    c_prow_split<<<gNNel, blk256, 0, stream>>>(S, rmaxv, rsumv, Ph, Pl);    // p_row pair
    c_padT_split<<<gPadT, bT, 0, stream>>>(fo, T1, T2);                     // output^T pair
    k_mfma3<6,3><<<gBig200, blk256, 0, stream>>>(Ph,Pl,T1,T2,
              sc1,nullptr,nullptr, nullptr, nullptr,maskf,cur,
              Nd, sNN,sT, 0.f);                                             // new_outs -> sc1
    c_pcolT_split<<<gPcolT, bT, 0, stream>>>(S, cmaxv, csumv, Ph, Pl);      // p_col^T pair
    c_padT_split<<<gPadT, bT, 0, stream>>>(cur, T3, T4);                    // outs^T pair (old)
    k_mfma3<7,3><<<gBig200, blk256, 0, stream>>>(Ph,Pl,T3,T4,
              fo,nullptr,nullptr, nullptr, nullptr,maskf,nullptr,
              Nd, sNN,sT, 0.f);                                             // fo update

    float* t = cur; cur = sc1; sc1 = t;   // outs = new_outs
  }

  k_store<<<gBNH, blk256, 0, stream>>>(cur, out_outs);
}

// Round 7
// 2321.740 us; speedup vs baseline: 2.5927x; 1.2788x over previous
//
#include <hip/hip_runtime.h>
#include <hip/hip_bf16.h>
#include <math.h>

// Problem constants
#define Bd 8
#define Nd 1024
#define Hd 200
#define HP 224                      // Hd padded to multiple of 32
#define BN (Bd*Nd)                  // 8192
#define SZ_BNH ((size_t)BN*Hd)      // 1,638,400
#define SZ_BNN ((size_t)BN*Nd)      // 8,388,608
#define SZ_PAD ((size_t)BN*HP)      // 1,835,008

typedef __hip_bfloat16 bf16;
typedef __attribute__((ext_vector_type(8))) short bf16x8;   // 8 bf16 = 4 VGPRs (A/B frag)
typedef __attribute__((ext_vector_type(4))) float f32x4;    // C/D frag

__device__ __forceinline__ float bf2f(bf16 v){ return __bfloat162float(v); }
__device__ __forceinline__ bf16 f2bf(float v){ return __float2bfloat16(v); }

#define MFMA16(a,b,c) __builtin_amdgcn_mfma_f32_16x16x32_bf16((a),(b),(c),0,0,0)

// ============================ prep (fp32) ============================
__global__ void k_prep_masks(const float* __restrict__ tm, float* __restrict__ maskf,
                             float* __restrict__ maskadd){
  int i = blockIdx.x*256 + threadIdx.x;
  if (i < BN){ float m = tm[i]; maskf[i] = m; maskadd[i] = (1.f - m) * -10000.f; }
}

__global__ void k_prep_adj(const float* __restrict__ a1, const float* __restrict__ a2,
                           float* __restrict__ adj_out, float* __restrict__ denom){
  int r = blockIdx.x;
  const size_t base = (size_t)r * Nd;
  int t = threadIdx.x;
  float s = 0.f;
  for (int m = t; m < Nd; m += 256){
    float a = a1[base+m] + a2[base+m];
    a = a >= 1.f ? 1.f : a;
    adj_out[base+m] = a;
    s += a;
  }
  __shared__ float red[256];
  red[t] = s; __syncthreads();
  for (int st = 128; st > 0; st >>= 1){ if (t < st) red[t] += red[t+st]; __syncthreads(); }
  if (t == 0) denom[r] = red[0] + 1e-07f;
}

__global__ void k_copy2(const float* __restrict__ x, float* __restrict__ o1,
                        float* __restrict__ o2){
  size_t i = (size_t)blockIdx.x*256 + threadIdx.x;
  if (i < SZ_BNH){ float v = x[i]; o1[i] = v; o2[i] = v; }
}

// ============================ split conversions ============================
__global__ void c_pad_split(const float* __restrict__ X, bf16* __restrict__ Oh,
                            bf16* __restrict__ Ol){
  size_t i = (size_t)blockIdx.x*256 + threadIdx.x;
  if (i >= SZ_PAD) return;
  int c = (int)(i % HP); size_t r = i / HP;
  float v = (c < Hd) ? X[r*Hd + c] : 0.f;
  bf16 h = f2bf(v);
  Oh[i] = h; Ol[i] = f2bf(v - bf2f(h));
}

__global__ void c_padT_split(const float* __restrict__ X, bf16* __restrict__ Oh,
                             bf16* __restrict__ Ol){
  __shared__ float t[32][33];
  int b = blockIdx.z, m0 = blockIdx.x*32, d0 = blockIdx.y*32;
  int tx = threadIdx.x, ty = threadIdx.y;          // block (32,8)
  for (int i = ty; i < 32; i += 8){
    int d = d0 + tx;
    t[i][tx] = (d < Hd) ? X[((size_t)b*Nd + m0+i)*Hd + d] : 0.f;
  }
  __syncthreads();
  for (int i = ty; i < 32; i += 8){
    size_t idx = (size_t)b*HP*Nd + (size_t)(d0+i)*Nd + m0 + tx;
    float v = t[tx][i];
    bf16 h = f2bf(v);
    Oh[idx] = h; Ol[idx] = f2bf(v - bf2f(h));
  }
}

__global__ void c_w_split(const float* __restrict__ W, bf16* __restrict__ Oh,
                          bf16* __restrict__ Ol){
  int i = blockIdx.x*256 + threadIdx.x;
  if (i >= HP*HP) return;
  int n = i / HP, k = i % HP;
  float v = (n < Hd && k < Hd) ? W[k*Hd + n] : 0.f;
  bf16 h = f2bf(v);
  Oh[i] = h; Ol[i] = f2bf(v - bf2f(h));
}

__global__ void c_cvt1024(const float* __restrict__ X, bf16* __restrict__ O){
  size_t i = (size_t)blockIdx.x*256 + threadIdx.x;
  if (i < SZ_BNN) O[i] = f2bf(X[i]);
}

__global__ void c_prow(const float* __restrict__ S, const float* __restrict__ rmax,
                       const float* __restrict__ rsum, bf16* __restrict__ P){
  size_t i = (size_t)blockIdx.x*256 + threadIdx.x;
  if (i >= SZ_BNN) return;
  size_t r = i >> 10;
  P[i] = f2bf(expf(S[i] - rmax[r]) * (1.f / rsum[r]));
}

__global__ void c_prow_split(const float* __restrict__ S, const float* __restrict__ rmax,
                             const float* __restrict__ rsum, bf16* __restrict__ Ph,
                             bf16* __restrict__ Pl){
  size_t i = (size_t)blockIdx.x*256 + threadIdx.x;
  if (i >= SZ_BNN) return;
  size_t r = i >> 10;
  float p = expf(S[i] - rmax[r]) * (1.f / rsum[r]);
  bf16 h = f2bf(p);
  Ph[i] = h; Pl[i] = f2bf(p - bf2f(h));
}

__global__ void c_pcolT_split(const float* __restrict__ S, const float* __restrict__ cmax,
                              const float* __restrict__ csum, bf16* __restrict__ Ph,
                              bf16* __restrict__ Pl){
  __shared__ float t[32][33];
  int b = blockIdx.z, n0 = blockIdx.x*32, m0 = blockIdx.y*32;
  int tx = threadIdx.x, ty = threadIdx.y;          // block (32,8)
  for (int i = ty; i < 32; i += 8)
    t[i][tx] = S[(size_t)b*Nd*Nd + (size_t)(n0+i)*Nd + m0 + tx];
  __syncthreads();
  for (int i = ty; i < 32; i += 8){
    int m = m0 + i;
    float cm = cmax[b*Nd + m], ci = 1.f / csum[b*Nd + m];
    float p = expf(t[tx][i] - cm) * ci;
    size_t idx = (size_t)b*Nd*Nd + (size_t)m*Nd + n0 + tx;
    bf16 h = f2bf(p);
    Ph[idx] = h; Pl[idx] = f2bf(p - bf2f(h));
  }
}

// ============================ softmax stats (fp32) ============================
__global__ void k_rowstats(const float* __restrict__ S, float* __restrict__ rmax,
                           float* __restrict__ rsum){
  size_t r = blockIdx.x;
  const float* row = S + r*Nd;
  int t = threadIdx.x;
  __shared__ float red[256];
  float mx = -3.4e38f;
  for (int i = t; i < Nd; i += 256) mx = fmaxf(mx, row[i]);
  red[t] = mx; __syncthreads();
  for (int s = 128; s > 0; s >>= 1){ if (t < s) red[t] = fmaxf(red[t], red[t+s]); __syncthreads(); }
  mx = red[0]; __syncthreads();
  float sum = 0.f;
  for (int i = t; i < Nd; i += 256) sum += expf(row[i] - mx);
  red[t] = sum; __syncthreads();
  for (int s = 128; s > 0; s >>= 1){ if (t < s) red[t] += red[t+s]; __syncthreads(); }
  if (t == 0){ rmax[r] = mx; rsum[r] = red[0]; }
}

__global__ void k_colstats(const float* __restrict__ S, float* __restrict__ cmax,
                           float* __restrict__ csum){
  int b = blockIdx.y;
  int tx = threadIdx.x & 63, ty = threadIdx.x >> 6;
  int m = blockIdx.x*64 + tx;
  const float* Sbp = S + (size_t)b*Nd*Nd;
  __shared__ float red[256];
  float mx = -3.4e38f;
  for (int n = ty; n < Nd; n += 4) mx = fmaxf(mx, Sbp[(size_t)n*Nd + m]);
  red[threadIdx.x] = mx; __syncthreads();
  if (ty == 0) red[tx] = fmaxf(fmaxf(red[tx], red[64+tx]), fmaxf(red[128+tx], red[192+tx]));
  __syncthreads();
  mx = red[tx]; __syncthreads();
  float s = 0.f;
  for (int n = ty; n < Nd; n += 4) s += expf(Sbp[(size_t)n*Nd + m] - mx);
  red[threadIdx.x] = s; __syncthreads();
  if (ty == 0){
    float tot = red[tx] + red[64+tx] + red[128+tx] + red[192+tx];
    cmax[b*Nd + m] = mx; csum[b*Nd + m] = tot;
  }
}

// ============================ residual + layernorm ============================
__global__ void k_add_ln(const float* __restrict__ X, const float* __restrict__ R,
                         const float* __restrict__ g, const float* __restrict__ bb,
                         float* __restrict__ Y){
  int r = blockIdx.x, t = threadIdx.x;
  __shared__ float red[256];
  bool act = t < Hd;
  float v = 0.f;
  if (act) v = X[(size_t)r*Hd + t] + R[(size_t)r*Hd + t];
  red[t] = act ? v : 0.f; __syncthreads();
  for (int s = 128; s > 0; s >>= 1){ if (t < s) red[t] += red[t+s]; __syncthreads(); }
  float mu = red[0] * (1.f/Hd); __syncthreads();
  float d = act ? (v - mu) : 0.f;
  red[t] = d*d; __syncthreads();
  for (int s = 128; s > 0; s >>= 1){ if (t < s) red[t] += red[t+s]; __syncthreads(); }
  float var = red[0] * (1.f/Hd);
  if (act){
    float rs = 1.f / sqrtf(var + 1e-20f);
    Y[(size_t)r*Hd + t] = (v - mu) * rs * g[t] + bb[t];
  }
}

__global__ void k_store(const float* __restrict__ X, float* __restrict__ O){
  size_t i = (size_t)blockIdx.x*256 + threadIdx.x;
  if (i < SZ_BNH) O[i] = X[i];
}

// ============================ split-precision MFMA GEMM, 2x2 tiles/wave =========
// D[m][n] = sum_k A[m][k]*B[n][k] (NT) with A = Ah+Al, B = Bh+Bl (Dekker split).
// TERMS=3: Ah*Bh + Ah*Bl + Al*Bh. TERMS=2: Ah*(Bh+Bl), A exact.
// Each wave computes a 32x32 output tile (2x2 MFMA tiles) for ILP + load amortization.
// Block = 4 waves stacked in M: 128 rows x 32 cols. Requires M%128==0, N%32==0.
// Frag: [idx=lane&15][k=(lane>>4)*8+j]; C/D: col=lane&15, row=(lane>>4)*4+reg.
// EPI: 0 fp32 Y=acc+bias  1 +gelu  2 split-bf16pad out (Ybh/Ybl)
//      3 S=acc*scale+maskadd[col]  4 S=acc+pairmask  5 Y+=relu(acc/denom[row])
//      6 Y=acc*maskf[row]+R  7 Y=acc*maskf[row]+Y
template<int EPI, int TERMS>
__global__ __launch_bounds__(256)
void k_mfma3(const bf16* __restrict__ Ah, const bf16* __restrict__ Al,
             const bf16* __restrict__ Bh, const bf16* __restrict__ Bl,
             float* __restrict__ Y, bf16* __restrict__ Ybh, bf16* __restrict__ Ybl,
             const float* __restrict__ bias, const float* __restrict__ e0,
             const float* __restrict__ e1, const float* __restrict__ R,
             int Kp, size_t sAb, size_t sBb, float scale)
{
  int b = blockIdx.z;
  int wave = threadIdx.x >> 6, lane = threadIdx.x & 63;
  int r0 = (blockIdx.y*4 + wave)*32;      // 32 rows per wave
  int c0 = blockIdx.x*32;                 // 32 cols per wave
  int lm = lane & 15, lq = lane >> 4;
  size_t a0 = (size_t)b*sAb + (size_t)(r0+lm)*Kp + lq*8;
  size_t bo = (size_t)b*sBb + (size_t)(c0+lm)*Kp + lq*8;
  const bf16* pA0h = Ah + a0;
  const bf16* pA1h = Ah + a0 + (size_t)16*Kp;
  const bf16* pB0h = Bh + bo;
  const bf16* pB1h = Bh + bo + (size_t)16*Kp;
  const bf16* pB0l = Bl + bo;
  const bf16* pB1l = Bl + bo + (size_t)16*Kp;
  const bf16* pA0l = (TERMS >= 3) ? (Al + a0) : nullptr;
  const bf16* pA1l = (TERMS >= 3) ? (Al + a0 + (size_t)16*Kp) : nullptr;

  f32x4 acc00 = {0,0,0,0}, acc01 = {0,0,0,0}, acc10 = {0,0,0,0}, acc11 = {0,0,0,0};
  for (int k = 0; k < Kp; k += 32){
    bf16x8 a0h = *(const bf16x8*)(pA0h + k);
    bf16x8 a1h = *(const bf16x8*)(pA1h + k);
    bf16x8 b0h = *(const bf16x8*)(pB0h + k);
    bf16x8 b1h = *(const bf16x8*)(pB1h + k);
    bf16x8 b0l = *(const bf16x8*)(pB0l + k);
    bf16x8 b1l = *(const bf16x8*)(pB1l + k);
    acc00 = MFMA16(a0h, b0h, acc00);
    acc01 = MFMA16(a0h, b1h, acc01);
    acc10 = MFMA16(a1h, b0h, acc10);
    acc11 = MFMA16(a1h, b1h, acc11);
    acc00 = MFMA16(a0h, b0l, acc00);
    acc01 = MFMA16(a0h, b1l, acc01);
    acc10 = MFMA16(a1h, b0l, acc10);
    acc11 = MFMA16(a1h, b1l, acc11);
    if (TERMS >= 3){
      bf16x8 a0l = *(const bf16x8*)(pA0l + k);
      bf16x8 a1l = *(const bf16x8*)(pA1l + k);
      acc00 = MFMA16(a0l, b0h, acc00);
      acc01 = MFMA16(a0l, b1h, acc01);
      acc10 = MFMA16(a1l, b0h, acc10);
      acc11 = MFMA16(a1l, b1h, acc11);
    }
  }

  #pragma unroll
  for (int i = 0; i < 2; i++){
    #pragma unroll
    for (int j = 0; j < 2; j++){
      f32x4 acc = (i==0) ? (j==0?acc00:acc01) : (j==0?acc10:acc11);
      int col = c0 + j*16 + lm;
      int rbase = r0 + i*16 + lq*4;
      #pragma unroll
      for (int r = 0; r < 4; r++){
        int row = rbase + r;
        size_t rowg = (size_t)b*Nd + row;
        float v = acc[r];
        if (EPI == 0 || EPI == 1){
          if (col < Hd){
            v += bias ? bias[col] : 0.f;
            if (EPI == 1) v = 0.5f*v*(1.f + erff(v*0.7071067811865476f));
            Y[rowg*Hd + col] = v;
          }
        } else if (EPI == 2){
          float o = (col < Hd) ? v + (bias ? bias[col] : 0.f) : 0.f;
          bf16 h = f2bf(o);
          Ybh[rowg*HP + col] = h;
          Ybl[rowg*HP + col] = f2bf(o - bf2f(h));
        } else if (EPI == 3){
          Y[rowg*Nd + col] = v*scale + e0[b*Nd + col];
        } else if (EPI == 4){
          Y[rowg*Nd + col] = v + (1.f - e1[b*Nd+row]*e1[b*Nd+col])*(-10000.f);
        } else if (EPI == 5){
          if (col < Hd){
            float u = v / e0[b*Nd+row]; u = u > 0.f ? u : 0.f;
            Y[rowg*Hd + col] += u;
          }
        } else if (EPI == 6){
          if (col < Hd) Y[rowg*Hd+col] = v*e1[b*Nd+row] + R[rowg*Hd+col];
        } else if (EPI == 7){
          if (col < Hd) Y[rowg*Hd+col] = v*e1[b*Nd+row] + Y[rowg*Hd+col];
        }
      }
    }
  }
}

// ============================ host launch ============================
static inline char* carve(char*& p, size_t bytes){
  char* r = p;
  p += (bytes + 511) & ~(size_t)511;
  return r;
}

extern "C" void kernel_launch(void* const* d_in, const int* in_sizes, int n_in,
                              void* d_out, int out_size, void* d_ws, size_t ws_size,
                              hipStream_t stream){
  (void)in_sizes; (void)n_in; (void)out_size; (void)ws_size;
  const float* text     = (const float*)d_in[0];
  const float* adj1     = (const float*)d_in[1];
  const float* adj2     = (const float*)d_in[2];
  const float* textmask = (const float*)d_in[5];
  const float* gcn_w    = (const float*)d_in[6];
  const float* mut_w    = (const float*)d_in[7];
  const float* qw = (const float*)d_in[8],  *qb = (const float*)d_in[9];
  const float* kw = (const float*)d_in[10], *kb = (const float*)d_in[11];
  const float* vw = (const float*)d_in[12], *vb = (const float*)d_in[13];
  const float* aow= (const float*)d_in[14], *aob= (const float*)d_in[15];
  const float* g1 = (const float*)d_in[16], *b1 = (const float*)d_in[17];
  const float* iw = (const float*)d_in[18], *ib = (const float*)d_in[19];
  const float* ow = (const float*)d_in[20], *ob = (const float*)d_in[21];
  const float* g2 = (const float*)d_in[22], *b2 = (const float*)d_in[23];

  float* out_outs = (float*)d_out;
  float* out_adj  = out_outs + SZ_BNH;

  // ---- workspace carve (~109 MB). out_outs doubles as fp32 scratch sc2. ----
  char* p = (char*)d_ws;
  float* cur  = (float*)carve(p, SZ_BNH*4);
  float* sc1  = (float*)carve(p, SZ_BNH*4);
  float* fo   = (float*)carve(p, SZ_BNH*4);
  float* S    = (float*)carve(p, SZ_BNN*4);           // fp32 scores / logits
  bf16*  Rb   = (bf16*)carve(p, SZ_BNN*2*2);          // big bf16 region (33.6 MB)
  bf16*  T1   = (bf16*)carve(p, SZ_PAD*2);
  bf16*  T2   = (bf16*)carve(p, SZ_PAD*2);
  bf16*  T3   = (bf16*)carve(p, SZ_PAD*2);
  bf16*  T4   = (bf16*)carve(p, SZ_PAD*2);
  bf16*  T5   = (bf16*)carve(p, SZ_PAD*2);
  bf16*  T6   = (bf16*)carve(p, SZ_PAD*2);
  bf16*  Wh   = (bf16*)carve(p, (size_t)HP*HP*2);
  bf16*  Wl   = (bf16*)carve(p, (size_t)HP*HP*2);
  float* denom   = (float*)carve(p, BN*4);
  float* maskf   = (float*)carve(p, BN*4);
  float* maskadd = (float*)carve(p, BN*4);
  float* rmaxv   = (float*)carve(p, BN*4);
  float* rsumv   = (float*)carve(p, BN*4);
  float* cmaxv   = (float*)carve(p, BN*4);
  float* csumv   = (float*)carve(p, BN*4);

  float* sc2 = out_outs;          // fp32 scratch; overwritten by final k_store
  bf16* attnP = Rb;               // phases: attnP -> adjb -> Ph/Pl (sequential)
  bf16* adjb  = Rb;
  bf16* Ph    = Rb;
  bf16* Pl    = Rb + SZ_BNN;

  const size_t sNT = (size_t)Nd*HP;     // batch stride, [1024][224]
  const size_t sT  = (size_t)HP*Nd;     // batch stride, [224][1024]
  const size_t sNN = (size_t)Nd*Nd;     // batch stride, [1024][1024]

  dim3 blk256(256);
  dim3 gPad((unsigned)((SZ_PAD+255)/256));
  dim3 gPadT(32, 7, Bd), bT(32, 8);
  dim3 gPcolT(32, 32, Bd);
  dim3 gW((HP*HP+255)/256);
  dim3 gNNel((unsigned)((SZ_BNN+255)/256));
  dim3 gBNH((unsigned)((SZ_BNH+255)/256));
  // GEMM grids: wave = 32x32 out, block = 128 rows x 32 cols
  dim3 gSm(7, 64, 1);        // small GEMM: 8192x224, K=HP
  dim3 gNT(32, 8, Bd);       // scores/logits: 1024x1024, K=HP
  dim3 gBig(7, 8, Bd);       // big mixes: 1024x224, K=1024
  const float inv_sqrt_h = 0.07071067811865475f;  // 1/sqrt(200)
  const size_t Z = 0;

  k_prep_masks<<<(BN+255)/256, blk256, 0, stream>>>(textmask, maskf, maskadd);
  k_prep_adj<<<BN, blk256, 0, stream>>>(adj1, adj2, out_adj, denom);
  k_copy2<<<gBNH, blk256, 0, stream>>>(text, cur, fo);

  for (int i = 0; i < 3; i++){
    const float *qwi = qw + i*Hd*Hd, *qbi = qb + i*Hd;
    const float *kwi = kw + i*Hd*Hd, *kbi = kb + i*Hd;
    const float *vwi = vw + i*Hd*Hd, *vbi = vb + i*Hd;
    const float *aowi= aow+ i*Hd*Hd, *aobi= aob+ i*Hd;
    const float *g1i = g1 + i*Hd,    *b1i = b1 + i*Hd;
    const float *iwi = iw + i*Hd*Hd, *ibi = ib + i*Hd;
    const float *owi = ow + i*Hd*Hd, *obi = ob + i*Hd;
    const float *g2i = g2 + i*Hd,    *b2i = b2 + i*Hd;

    // ================= BERT layer: cur -> cur =================
    c_pad_split<<<gPad, blk256, 0, stream>>>(cur, T1, T2);                  // cur pair
    c_w_split<<<gW, blk256, 0, stream>>>(qwi, Wh, Wl);
    k_mfma3<2,3><<<gSm, blk256, 0, stream>>>(T1,T2,Wh,Wl, nullptr,T3,T4,
              qbi, nullptr,nullptr,nullptr, HP, Z,Z, 0.f);                  // Q pair
    c_w_split<<<gW, blk256, 0, stream>>>(kwi, Wh, Wl);
    k_mfma3<2,3><<<gSm, blk256, 0, stream>>>(T1,T2,Wh,Wl, nullptr,T5,T6,
              kbi, nullptr,nullptr,nullptr, HP, Z,Z, 0.f);                  // K pair
    k_mfma3<3,3><<<gNT, blk256, 0, stream>>>(T3,T4,T5,T6, S,nullptr,nullptr,
              nullptr, maskadd,nullptr,nullptr, HP, sNT,sNT, inv_sqrt_h);   // scores
    c_w_split<<<gW, blk256, 0, stream>>>(vwi, Wh, Wl);
    k_mfma3<0,3><<<gSm, blk256, 0, stream>>>(T1,T2,Wh,Wl, sc1,nullptr,nullptr,
              vbi, nullptr,nullptr,nullptr, HP, Z,Z, 0.f);                  // V fp32
    k_rowstats<<<BN, blk256, 0, stream>>>(S, rmaxv, rsumv);
    c_prow<<<gNNel, blk256, 0, stream>>>(S, rmaxv, rsumv, attnP);           // probs (single)
    c_padT_split<<<gPadT, bT, 0, stream>>>(sc1, T1, T2);                    // V^T pair
    k_mfma3<0,2><<<gBig, blk256, 0, stream>>>(attnP,nullptr,T1,T2,
              sc2,nullptr,nullptr, nullptr, nullptr,nullptr,nullptr,
              Nd, sNN,sT, 0.f);                                             // ctx
    c_pad_split<<<gPad, blk256, 0, stream>>>(sc2, T3, T4);
    c_w_split<<<gW, blk256, 0, stream>>>(aowi, Wh, Wl);
    k_mfma3<0,3><<<gSm, blk256, 0, stream>>>(T3,T4,Wh,Wl, sc1,nullptr,nullptr,
              aobi, nullptr,nullptr,nullptr, HP, Z,Z, 0.f);                 // ao_out
    k_add_ln<<<BN, blk256, 0, stream>>>(sc1, cur, g1i, b1i, sc2);           // attn -> sc2
    c_pad_split<<<gPad, blk256, 0, stream>>>(sc2, T1, T2);
    c_w_split<<<gW, blk256, 0, stream>>>(iwi, Wh, Wl);
    k_mfma3<1,3><<<gSm, blk256, 0, stream>>>(T1,T2,Wh,Wl, sc1,nullptr,nullptr,
              ibi, nullptr,nullptr,nullptr, HP, Z,Z, 0.f);                  // gelu(inter)
    c_pad_split<<<gPad, blk256, 0, stream>>>(sc1, T3, T4);
    c_w_split<<<gW, blk256, 0, stream>>>(owi, Wh, Wl);
    k_mfma3<0,3><<<gSm, blk256, 0, stream>>>(T3,T4,Wh,Wl, cur,nullptr,nullptr,
              obi, nullptr,nullptr,nullptr, HP, Z,Z, 0.f);                  // ow_out -> cur
    k_add_ln<<<BN, blk256, 0, stream>>>(cur, sc2, g2i, b2i, cur);           // bert out

    // ================= GCN on fo =================
    c_pad_split<<<gPad, blk256, 0, stream>>>(fo, T1, T2);
    c_w_split<<<gW, blk256, 0, stream>>>(gcn_w, Wh, Wl);
    k_mfma3<0,3><<<gSm, blk256, 0, stream>>>(T1,T2,Wh,Wl, sc1,nullptr,nullptr,
              nullptr, nullptr,nullptr,nullptr, HP, Z,Z, 0.f);              // teout
    c_padT_split<<<gPadT, bT, 0, stream>>>(sc1, T3, T4);                    // teout^T pair
    c_cvt1024<<<gNNel, blk256, 0, stream>>>(out_adj, adjb);                 // adj bf16 exact
    k_mfma3<5,2><<<gBig, blk256, 0, stream>>>(adjb,nullptr,T3,T4,
              fo,nullptr,nullptr, nullptr, denom,nullptr,nullptr,
              Nd, sNN,sT, 0.f);                                             // fo += relu(./denom)

    // ================= self-alignment =================
    c_pad_split<<<gPad, blk256, 0, stream>>>(cur, T1, T2);
    c_w_split<<<gW, blk256, 0, stream>>>(mut_w, Wh, Wl);
    k_mfma3<2,3><<<gSm, blk256, 0, stream>>>(T1,T2,Wh,Wl, nullptr,T5,T6,
              nullptr, nullptr,nullptr,nullptr, HP, Z,Z, 0.f);              // mm pair
    c_pad_split<<<gPad, blk256, 0, stream>>>(fo, T1, T2);                   // fo pad pair
    k_mfma3<4,3><<<gNT, blk256, 0, stream>>>(T5,T6,T1,T2, S,nullptr,nullptr,
              nullptr, nullptr,maskf,nullptr, HP, sNT,sNT, 0.f);            // logits -> S
    k_colstats<<<dim3(Nd/64, Bd), blk256, 0, stream>>>(S, cmaxv, csumv);
    k_rowstats<<<BN, blk256, 0, stream>>>(S, rmaxv, rsumv);
    c_prow_split<<<gNNel, blk256, 0, stream>>>(S, rmaxv, rsumv, Ph, Pl);    // p_row pair
    c_padT_split<<<gPadT, bT, 0, stream>>>(fo, T1, T2);                     // output^T pair
    k_mfma3<6,3><<<gBig, blk256, 0, stream>>>(Ph,Pl,T1,T2,
              sc1,nullptr,nullptr, nullptr, nullptr,maskf,cur,
              Nd, sNN,sT, 0.f);                                             // new_outs -> sc1
    c_pcolT_split<<<gPcolT, bT, 0, stream>>>(S, cmaxv, csumv, Ph, Pl);      // p_col^T pair
    c_padT_split<<<gPadT, bT, 0, stream>>>(cur, T3, T4);                    // outs^T pair (old)
    k_mfma3<7,3><<<gBig, blk256, 0, stream>>>(Ph,Pl,T3,T4,
              fo,nullptr,nullptr, nullptr, nullptr,maskf,nullptr,
              Nd, sNN,sT, 0.f);                                             // fo update

    float* t = cur; cur = sc1; sc1 = t;   // outs = new_outs
  }

  k_store<<<gBNH, blk256, 0, stream>>>(cur, out_outs);
}

// Round 8
// 2125.440 us; speedup vs baseline: 2.8322x; 1.0924x over previous
//
#include <hip/hip_runtime.h>
#include <hip/hip_bf16.h>
#include <math.h>

// Problem constants
#define Bd 8
#define Nd 1024
#define Hd 200
#define HP 224                      // Hd padded to multiple of 32
#define BN (Bd*Nd)                  // 8192
#define SZ_BNH ((size_t)BN*Hd)      // 1,638,400
#define SZ_BNN ((size_t)BN*Nd)      // 8,388,608
#define SZ_PAD ((size_t)BN*HP)      // 1,835,008

typedef __hip_bfloat16 bf16;
typedef __attribute__((ext_vector_type(8))) short bf16x8;   // 8 bf16 = 4 VGPRs (A/B frag)
typedef __attribute__((ext_vector_type(4))) float f32x4;    // C/D frag

__device__ __forceinline__ float bf2f(bf16 v){ return __bfloat162float(v); }
__device__ __forceinline__ bf16 f2bf(float v){ return __float2bfloat16(v); }

#define MFMA16(a,b,c) __builtin_amdgcn_mfma_f32_16x16x32_bf16((a),(b),(c),0,0,0)

// ============================ prep (fp32) ============================
__global__ void k_prep_masks(const float* __restrict__ tm, float* __restrict__ maskf,
                             float* __restrict__ maskadd){
  int i = blockIdx.x*256 + threadIdx.x;
  if (i < BN){ float m = tm[i]; maskf[i] = m; maskadd[i] = (1.f - m) * -10000.f; }
}

__global__ void k_prep_adj(const float* __restrict__ a1, const float* __restrict__ a2,
                           float* __restrict__ adj_out, float* __restrict__ denom){
  int r = blockIdx.x;
  const size_t base = (size_t)r * Nd;
  int t = threadIdx.x;
  float s = 0.f;
  for (int m = t; m < Nd; m += 256){
    float a = a1[base+m] + a2[base+m];
    a = a >= 1.f ? 1.f : a;
    adj_out[base+m] = a;
    s += a;
  }
  __shared__ float red[256];
  red[t] = s; __syncthreads();
  for (int st = 128; st > 0; st >>= 1){ if (t < st) red[t] += red[t+st]; __syncthreads(); }
  if (t == 0) denom[r] = red[0] + 1e-07f;
}

__global__ void k_copy2(const float* __restrict__ x, float* __restrict__ o1,
                        float* __restrict__ o2){
  size_t i = (size_t)blockIdx.x*256 + threadIdx.x;
  if (i < SZ_BNH){ float v = x[i]; o1[i] = v; o2[i] = v; }
}

// ============================ split conversions ============================
__global__ void c_pad_split(const float* __restrict__ X, bf16* __restrict__ Oh,
                            bf16* __restrict__ Ol){
  size_t i = (size_t)blockIdx.x*256 + threadIdx.x;
  if (i >= SZ_PAD) return;
  int c = (int)(i % HP); size_t r = i / HP;
  float v = (c < Hd) ? X[r*Hd + c] : 0.f;
  bf16 h = f2bf(v);
  Oh[i] = h; Ol[i] = f2bf(v - bf2f(h));
}

__global__ void c_padT_split(const float* __restrict__ X, bf16* __restrict__ Oh,
                             bf16* __restrict__ Ol){
  __shared__ float t[32][33];
  int b = blockIdx.z, m0 = blockIdx.x*32, d0 = blockIdx.y*32;
  int tx = threadIdx.x, ty = threadIdx.y;          // block (32,8)
  for (int i = ty; i < 32; i += 8){
    int d = d0 + tx;
    t[i][tx] = (d < Hd) ? X[((size_t)b*Nd + m0+i)*Hd + d] : 0.f;
  }
  __syncthreads();
  for (int i = ty; i < 32; i += 8){
    size_t idx = (size_t)b*HP*Nd + (size_t)(d0+i)*Nd + m0 + tx;
    float v = t[tx][i];
    bf16 h = f2bf(v);
    Oh[idx] = h; Ol[idx] = f2bf(v - bf2f(h));
  }
}

__global__ void c_w_split(const float* __restrict__ W, bf16* __restrict__ Oh,
                          bf16* __restrict__ Ol){
  int i = blockIdx.x*256 + threadIdx.x;
  if (i >= HP*HP) return;
  int n = i / HP, k = i % HP;
  float v = (n < Hd && k < Hd) ? W[k*Hd + n] : 0.f;
  bf16 h = f2bf(v);
  Oh[i] = h; Ol[i] = f2bf(v - bf2f(h));
}

__global__ void c_cvt1024(const float* __restrict__ X, bf16* __restrict__ O){
  size_t i = (size_t)blockIdx.x*256 + threadIdx.x;
  if (i < SZ_BNN) O[i] = f2bf(X[i]);
}

__global__ void c_prow(const float* __restrict__ S, const float* __restrict__ rmax,
                       const float* __restrict__ rsum, bf16* __restrict__ P){
  size_t i = (size_t)blockIdx.x*256 + threadIdx.x;
  if (i >= SZ_BNN) return;
  size_t r = i >> 10;
  P[i] = f2bf(expf(S[i] - rmax[r]) * (1.f / rsum[r]));
}

__global__ void c_prow_split(const float* __restrict__ S, const float* __restrict__ rmax,
                             const float* __restrict__ rsum, bf16* __restrict__ Ph,
                             bf16* __restrict__ Pl){
  size_t i = (size_t)blockIdx.x*256 + threadIdx.x;
  if (i >= SZ_BNN) return;
  size_t r = i >> 10;
  float p = expf(S[i] - rmax[r]) * (1.f / rsum[r]);
  bf16 h = f2bf(p);
  Ph[i] = h; Pl[i] = f2bf(p - bf2f(h));
}

__global__ void c_pcolT_split(const float* __restrict__ S, const float* __restrict__ cmax,
                              const float* __restrict__ csum, bf16* __restrict__ Ph,
                              bf16* __restrict__ Pl){
  __shared__ float t[32][33];
  int b = blockIdx.z, n0 = blockIdx.x*32, m0 = blockIdx.y*32;
  int tx = threadIdx.x, ty = threadIdx.y;          // block (32,8)
  for (int i = ty; i < 32; i += 8)
    t[i][tx] = S[(size_t)b*Nd*Nd + (size_t)(n0+i)*Nd + m0 + tx];
  __syncthreads();
  for (int i = ty; i < 32; i += 8){
    int m = m0 + i;
    float cm = cmax[b*Nd + m], ci = 1.f / csum[b*Nd + m];
    float p = expf(t[tx][i] - cm) * ci;
    size_t idx = (size_t)b*Nd*Nd + (size_t)m*Nd + n0 + tx;
    bf16 h = f2bf(p);
    Ph[idx] = h; Pl[idx] = f2bf(p - bf2f(h));
  }
}

// ============================ softmax stats (fp32) ============================
__global__ void k_rowstats(const float* __restrict__ S, float* __restrict__ rmax,
                           float* __restrict__ rsum){
  size_t r = blockIdx.x;
  const float* row = S + r*Nd;
  int t = threadIdx.x;
  __shared__ float red[256];
  float mx = -3.4e38f;
  for (int i = t; i < Nd; i += 256) mx = fmaxf(mx, row[i]);
  red[t] = mx; __syncthreads();
  for (int s = 128; s > 0; s >>= 1){ if (t < s) red[t] = fmaxf(red[t], red[t+s]); __syncthreads(); }
  mx = red[0]; __syncthreads();
  float sum = 0.f;
  for (int i = t; i < Nd; i += 256) sum += expf(row[i] - mx);
  red[t] = sum; __syncthreads();
  for (int s = 128; s > 0; s >>= 1){ if (t < s) red[t] += red[t+s]; __syncthreads(); }
  if (t == 0){ rmax[r] = mx; rsum[r] = red[0]; }
}

// Single-pass online column softmax stats. 1024 threads: 64 cols x 16 row-groups.
// Each thread keeps a running (max,sum) with rescaling; LDS tree-combine.
__global__ __launch_bounds__(1024)
void k_colstats(const float* __restrict__ S, float* __restrict__ cmax,
                float* __restrict__ csum){
  int b = blockIdx.y;
  int tx = threadIdx.x & 63, ty = threadIdx.x >> 6;   // ty in 0..15
  int m = blockIdx.x*64 + tx;
  const float* Sbp = S + (size_t)b*Nd*Nd + m;
  float mx = -3.4e38f, sm = 0.f;
  for (int n = ty; n < Nd; n += 16){
    float x = Sbp[(size_t)n*Nd];
    if (x > mx){ sm = sm * expf(mx - x) + 1.f; mx = x; }
    else        sm += expf(x - mx);
  }
  __shared__ float smx[16][64], ssm[16][64];
  smx[ty][tx] = mx; ssm[ty][tx] = sm;
  __syncthreads();
  for (int st = 8; st > 0; st >>= 1){
    if (ty < st){
      float m1 = smx[ty][tx],    s1 = ssm[ty][tx];
      float m2 = smx[ty+st][tx], s2 = ssm[ty+st][tx];
      float M = fmaxf(m1, m2);
      smx[ty][tx] = M;
      ssm[ty][tx] = s1*expf(m1 - M) + s2*expf(m2 - M);
    }
    __syncthreads();
  }
  if (ty == 0){ cmax[b*Nd + m] = smx[0][tx]; csum[b*Nd + m] = ssm[0][tx]; }
}

// ============================ residual + layernorm ============================
__global__ void k_add_ln(const float* __restrict__ X, const float* __restrict__ R,
                         const float* __restrict__ g, const float* __restrict__ bb,
                         float* __restrict__ Y){
  int r = blockIdx.x, t = threadIdx.x;
  __shared__ float red[256];
  bool act = t < Hd;
  float v = 0.f;
  if (act) v = X[(size_t)r*Hd + t] + R[(size_t)r*Hd + t];
  red[t] = act ? v : 0.f; __syncthreads();
  for (int s = 128; s > 0; s >>= 1){ if (t < s) red[t] += red[t+s]; __syncthreads(); }
  float mu = red[0] * (1.f/Hd); __syncthreads();
  float d = act ? (v - mu) : 0.f;
  red[t] = d*d; __syncthreads();
  for (int s = 128; s > 0; s >>= 1){ if (t < s) red[t] += red[t+s]; __syncthreads(); }
  float var = red[0] * (1.f/Hd);
  if (act){
    float rs = 1.f / sqrtf(var + 1e-20f);
    Y[(size_t)r*Hd + t] = (v - mu) * rs * g[t] + bb[t];
  }
}

__global__ void k_store(const float* __restrict__ X, float* __restrict__ O){
  size_t i = (size_t)blockIdx.x*256 + threadIdx.x;
  if (i < SZ_BNH) O[i] = X[i];
}

// ============================ split-precision MFMA GEMM, 2x2 tiles/wave =========
// D[m][n] = sum_k A[m][k]*B[n][k] (NT) with A = Ah+Al, B = Bh+Bl (Dekker split).
// TERMS=3: Ah*Bh + Ah*Bl + Al*Bh. TERMS=2: Ah*(Bh+Bl), A exact.
// Each wave computes a 32x32 output tile (2x2 MFMA tiles) for ILP + load amortization.
// Block = 4 waves stacked in M: 128 rows x 32 cols. Requires M%128==0, N%32==0.
// Frag: [idx=lane&15][k=(lane>>4)*8+j]; C/D: col=lane&15, row=(lane>>4)*4+reg.
// EPI: 0 fp32 Y=acc+bias  1 +gelu  2 split-bf16pad out (Ybh/Ybl)
//      3 S=acc*scale+maskadd[col]  4 S=acc+pairmask  5 Y+=relu(acc/denom[row])
//      6 Y=acc*maskf[row]+R  7 Y=acc*maskf[row]+Y
template<int EPI, int TERMS>
__global__ __launch_bounds__(256)
void k_mfma3(const bf16* __restrict__ Ah, const bf16* __restrict__ Al,
             const bf16* __restrict__ Bh, const bf16* __restrict__ Bl,
             float* __restrict__ Y, bf16* __restrict__ Ybh, bf16* __restrict__ Ybl,
             const float* __restrict__ bias, const float* __restrict__ e0,
             const float* __restrict__ e1, const float* __restrict__ R,
             int Kp, size_t sAb, size_t sBb, float scale)
{
  int b = blockIdx.z;
  int wave = threadIdx.x >> 6, lane = threadIdx.x & 63;
  int r0 = (blockIdx.y*4 + wave)*32;      // 32 rows per wave
  int c0 = blockIdx.x*32;                 // 32 cols per wave
  int lm = lane & 15, lq = lane >> 4;
  size_t a0 = (size_t)b*sAb + (size_t)(r0+lm)*Kp + lq*8;
  size_t bo = (size_t)b*sBb + (size_t)(c0+lm)*Kp + lq*8;
  const bf16* pA0h = Ah + a0;
  const bf16* pA1h = Ah + a0 + (size_t)16*Kp;
  const bf16* pB0h = Bh + bo;
  const bf16* pB1h = Bh + bo + (size_t)16*Kp;
  const bf16* pB0l = Bl + bo;
  const bf16* pB1l = Bl + bo + (size_t)16*Kp;
  const bf16* pA0l = (TERMS >= 3) ? (Al + a0) : nullptr;
  const bf16* pA1l = (TERMS >= 3) ? (Al + a0 + (size_t)16*Kp) : nullptr;

  f32x4 acc00 = {0,0,0,0}, acc01 = {0,0,0,0}, acc10 = {0,0,0,0}, acc11 = {0,0,0,0};
  for (int k = 0; k < Kp; k += 32){
    bf16x8 a0h = *(const bf16x8*)(pA0h + k);
    bf16x8 a1h = *(const bf16x8*)(pA1h + k);
    bf16x8 b0h = *(const bf16x8*)(pB0h + k);
    bf16x8 b1h = *(const bf16x8*)(pB1h + k);
    bf16x8 b0l = *(const bf16x8*)(pB0l + k);
    bf16x8 b1l = *(const bf16x8*)(pB1l + k);
    acc00 = MFMA16(a0h, b0h, acc00);
    acc01 = MFMA16(a0h, b1h, acc01);
    acc10 = MFMA16(a1h, b0h, acc10);
    acc11 = MFMA16(a1h, b1h, acc11);
    acc00 = MFMA16(a0h, b0l, acc00);
    acc01 = MFMA16(a0h, b1l, acc01);
    acc10 = MFMA16(a1h, b0l, acc10);
    acc11 = MFMA16(a1h, b1l, acc11);
    if (TERMS >= 3){
      bf16x8 a0l = *(const bf16x8*)(pA0l + k);
      bf16x8 a1l = *(const bf16x8*)(pA1l + k);
      acc00 = MFMA16(a0l, b0h, acc00);
      acc01 = MFMA16(a0l, b1h, acc01);
      acc10 = MFMA16(a1l, b0h, acc10);
      acc11 = MFMA16(a1l, b1h, acc11);
    }
  }

  #pragma unroll
  for (int i = 0; i < 2; i++){
    #pragma unroll
    for (int j = 0; j < 2; j++){
      f32x4 acc = (i==0) ? (j==0?acc00:acc01) : (j==0?acc10:acc11);
      int col = c0 + j*16 + lm;
      int rbase = r0 + i*16 + lq*4;
      #pragma unroll
      for (int r = 0; r < 4; r++){
        int row = rbase + r;
        size_t rowg = (size_t)b*Nd + row;
        float v = acc[r];
        if (EPI == 0 || EPI == 1){
          if (col < Hd){
            v += bias ? bias[col] : 0.f;
            if (EPI == 1) v = 0.5f*v*(1.f + erff(v*0.7071067811865476f));
            Y[rowg*Hd + col] = v;
          }
        } else if (EPI == 2){
          float o = (col < Hd) ? v + (bias ? bias[col] : 0.f) : 0.f;
          bf16 h = f2bf(o);
          Ybh[rowg*HP + col] = h;
          Ybl[rowg*HP + col] = f2bf(o - bf2f(h));
        } else if (EPI == 3){
          Y[rowg*Nd + col] = v*scale + e0[b*Nd + col];
        } else if (EPI == 4){
          Y[rowg*Nd + col] = v + (1.f - e1[b*Nd+row]*e1[b*Nd+col])*(-10000.f);
        } else if (EPI == 5){
          if (col < Hd){
            float u = v / e0[b*Nd+row]; u = u > 0.f ? u : 0.f;
            Y[rowg*Hd + col] += u;
          }
        } else if (EPI == 6){
          if (col < Hd) Y[rowg*Hd+col] = v*e1[b*Nd+row] + R[rowg*Hd+col];
        } else if (EPI == 7){
          if (col < Hd) Y[rowg*Hd+col] = v*e1[b*Nd+row] + Y[rowg*Hd+col];
        }
      }
    }
  }
}

// ============================ host launch ============================
static inline char* carve(char*& p, size_t bytes){
  char* r = p;
  p += (bytes + 511) & ~(size_t)511;
  return r;
}

extern "C" void kernel_launch(void* const* d_in, const int* in_sizes, int n_in,
                              void* d_out, int out_size, void* d_ws, size_t ws_size,
                              hipStream_t stream){
  (void)in_sizes; (void)n_in; (void)out_size; (void)ws_size;
  const float* text     = (const float*)d_in[0];
  const float* adj1     = (const float*)d_in[1];
  const float* adj2     = (const float*)d_in[2];
  const float* textmask = (const float*)d_in[5];
  const float* gcn_w    = (const float*)d_in[6];
  const float* mut_w    = (const float*)d_in[7];
  const float* qw = (const float*)d_in[8],  *qb = (const float*)d_in[9];
  const float* kw = (const float*)d_in[10], *kb = (const float*)d_in[11];
  const float* vw = (const float*)d_in[12], *vb = (const float*)d_in[13];
  const float* aow= (const float*)d_in[14], *aob= (const float*)d_in[15];
  const float* g1 = (const float*)d_in[16], *b1 = (const float*)d_in[17];
  const float* iw = (const float*)d_in[18], *ib = (const float*)d_in[19];
  const float* ow = (const float*)d_in[20], *ob = (const float*)d_in[21];
  const float* g2 = (const float*)d_in[22], *b2 = (const float*)d_in[23];

  float* out_outs = (float*)d_out;
  float* out_adj  = out_outs + SZ_BNH;

  // ---- workspace carve (~109 MB). out_outs doubles as fp32 scratch sc2. ----
  char* p = (char*)d_ws;
  float* cur  = (float*)carve(p, SZ_BNH*4);
  float* sc1  = (float*)carve(p, SZ_BNH*4);
  float* fo   = (float*)carve(p, SZ_BNH*4);
  float* S    = (float*)carve(p, SZ_BNN*4);           // fp32 scores / logits
  bf16*  Rb   = (bf16*)carve(p, SZ_BNN*2*2);          // big bf16 region (33.6 MB)
  bf16*  T1   = (bf16*)carve(p, SZ_PAD*2);
  bf16*  T2   = (bf16*)carve(p, SZ_PAD*2);
  bf16*  T3   = (bf16*)carve(p, SZ_PAD*2);
  bf16*  T4   = (bf16*)carve(p, SZ_PAD*2);
  bf16*  T5   = (bf16*)carve(p, SZ_PAD*2);
  bf16*  T6   = (bf16*)carve(p, SZ_PAD*2);
  bf16*  Wh   = (bf16*)carve(p, (size_t)HP*HP*2);
  bf16*  Wl   = (bf16*)carve(p, (size_t)HP*HP*2);
  float* denom   = (float*)carve(p, BN*4);
  float* maskf   = (float*)carve(p, BN*4);
  float* maskadd = (float*)carve(p, BN*4);
  float* rmaxv   = (float*)carve(p, BN*4);
  float* rsumv   = (float*)carve(p, BN*4);
  float* cmaxv   = (float*)carve(p, BN*4);
  float* csumv   = (float*)carve(p, BN*4);

  float* sc2 = out_outs;          // fp32 scratch; overwritten by final k_store
  bf16* attnP = Rb;               // phases: attnP -> adjb -> Ph/Pl (sequential)
  bf16* adjb  = Rb;
  bf16* Ph    = Rb;
  bf16* Pl    = Rb + SZ_BNN;

  const size_t sNT = (size_t)Nd*HP;     // batch stride, [1024][224]
  const size_t sT  = (size_t)HP*Nd;     // batch stride, [224][1024]
  const size_t sNN = (size_t)Nd*Nd;     // batch stride, [1024][1024]

  dim3 blk256(256);
  dim3 gPad((unsigned)((SZ_PAD+255)/256));
  dim3 gPadT(32, 7, Bd), bT(32, 8);
  dim3 gPcolT(32, 32, Bd);
  dim3 gW((HP*HP+255)/256);
  dim3 gNNel((unsigned)((SZ_BNN+255)/256));
  dim3 gBNH((unsigned)((SZ_BNH+255)/256));
  // GEMM grids: wave = 32x32 out, block = 128 rows x 32 cols
  dim3 gSm(7, 64, 1);        // small GEMM: 8192x224, K=HP
  dim3 gNT(32, 8, Bd);       // scores/logits: 1024x1024, K=HP
  dim3 gBig(7, 8, Bd);       // big mixes: 1024x224, K=1024
  const float inv_sqrt_h = 0.07071067811865475f;  // 1/sqrt(200)
  const size_t Z = 0;

  k_prep_masks<<<(BN+255)/256, blk256, 0, stream>>>(textmask, maskf, maskadd);
  k_prep_adj<<<BN, blk256, 0, stream>>>(adj1, adj2, out_adj, denom);
  k_copy2<<<gBNH, blk256, 0, stream>>>(text, cur, fo);

  for (int i = 0; i < 3; i++){
    const float *qwi = qw + i*Hd*Hd, *qbi = qb + i*Hd;
    const float *kwi = kw + i*Hd*Hd, *kbi = kb + i*Hd;
    const float *vwi = vw + i*Hd*Hd, *vbi = vb + i*Hd;
    const float *aowi= aow+ i*Hd*Hd, *aobi= aob+ i*Hd;
    const float *g1i = g1 + i*Hd,    *b1i = b1 + i*Hd;
    const float *iwi = iw + i*Hd*Hd, *ibi = ib + i*Hd;
    const float *owi = ow + i*Hd*Hd, *obi = ob + i*Hd;
    const float *g2i = g2 + i*Hd,    *b2i = b2 + i*Hd;

    // ================= BERT layer: cur -> cur =================
    c_pad_split<<<gPad, blk256, 0, stream>>>(cur, T1, T2);                  // cur pair
    c_w_split<<<gW, blk256, 0, stream>>>(qwi, Wh, Wl);
    k_mfma3<2,3><<<gSm, blk256, 0, stream>>>(T1,T2,Wh,Wl, nullptr,T3,T4,
              qbi, nullptr,nullptr,nullptr, HP, Z,Z, 0.f);                  // Q pair
    c_w_split<<<gW, blk256, 0, stream>>>(kwi, Wh, Wl);
    k_mfma3<2,3><<<gSm, blk256, 0, stream>>>(T1,T2,Wh,Wl, nullptr,T5,T6,
              kbi, nullptr,nullptr,nullptr, HP, Z,Z, 0.f);                  // K pair
    k_mfma3<3,3><<<gNT, blk256, 0, stream>>>(T3,T4,T5,T6, S,nullptr,nullptr,
              nullptr, maskadd,nullptr,nullptr, HP, sNT,sNT, inv_sqrt_h);   // scores
    c_w_split<<<gW, blk256, 0, stream>>>(vwi, Wh, Wl);
    k_mfma3<0,3><<<gSm, blk256, 0, stream>>>(T1,T2,Wh,Wl, sc1,nullptr,nullptr,
              vbi, nullptr,nullptr,nullptr, HP, Z,Z, 0.f);                  // V fp32
    k_rowstats<<<BN, blk256, 0, stream>>>(S, rmaxv, rsumv);
    c_prow<<<gNNel, blk256, 0, stream>>>(S, rmaxv, rsumv, attnP);           // probs (single)
    c_padT_split<<<gPadT, bT, 0, stream>>>(sc1, T1, T2);                    // V^T pair
    k_mfma3<0,2><<<gBig, blk256, 0, stream>>>(attnP,nullptr,T1,T2,
              sc2,nullptr,nullptr, nullptr, nullptr,nullptr,nullptr,
              Nd, sNN,sT, 0.f);                                             // ctx
    c_pad_split<<<gPad, blk256, 0, stream>>>(sc2, T3, T4);
    c_w_split<<<gW, blk256, 0, stream>>>(aowi, Wh, Wl);
    k_mfma3<0,3><<<gSm, blk256, 0, stream>>>(T3,T4,Wh,Wl, sc1,nullptr,nullptr,
              aobi, nullptr,nullptr,nullptr, HP, Z,Z, 0.f);                 // ao_out
    k_add_ln<<<BN, blk256, 0, stream>>>(sc1, cur, g1i, b1i, sc2);           // attn -> sc2
    c_pad_split<<<gPad, blk256, 0, stream>>>(sc2, T1, T2);
    c_w_split<<<gW, blk256, 0, stream>>>(iwi, Wh, Wl);
    k_mfma3<1,3><<<gSm, blk256, 0, stream>>>(T1,T2,Wh,Wl, sc1,nullptr,nullptr,
              ibi, nullptr,nullptr,nullptr, HP, Z,Z, 0.f);                  // gelu(inter)
    c_pad_split<<<gPad, blk256, 0, stream>>>(sc1, T3, T4);
    c_w_split<<<gW, blk256, 0, stream>>>(owi, Wh, Wl);
    k_mfma3<0,3><<<gSm, blk256, 0, stream>>>(T3,T4,Wh,Wl, cur,nullptr,nullptr,
              obi, nullptr,nullptr,nullptr, HP, Z,Z, 0.f);                  // ow_out -> cur
    k_add_ln<<<BN, blk256, 0, stream>>>(cur, sc2, g2i, b2i, cur);           // bert out

    // ================= GCN on fo =================
    c_pad_split<<<gPad, blk256, 0, stream>>>(fo, T1, T2);
    c_w_split<<<gW, blk256, 0, stream>>>(gcn_w, Wh, Wl);
    k_mfma3<0,3><<<gSm, blk256, 0, stream>>>(T1,T2,Wh,Wl, sc1,nullptr,nullptr,
              nullptr, nullptr,nullptr,nullptr, HP, Z,Z, 0.f);              // teout
    c_padT_split<<<gPadT, bT, 0, stream>>>(sc1, T3, T4);                    // teout^T pair
    c_cvt1024<<<gNNel, blk256, 0, stream>>>(out_adj, adjb);                 // adj bf16 exact
    k_mfma3<5,2><<<gBig, blk256, 0, stream>>>(adjb,nullptr,T3,T4,
              fo,nullptr,nullptr, nullptr, denom,nullptr,nullptr,
              Nd, sNN,sT, 0.f);                                             // fo += relu(./denom)

    // ================= self-alignment =================
    c_pad_split<<<gPad, blk256, 0, stream>>>(cur, T1, T2);
    c_w_split<<<gW, blk256, 0, stream>>>(mut_w, Wh, Wl);
    k_mfma3<2,3><<<gSm, blk256, 0, stream>>>(T1,T2,Wh,Wl, nullptr,T5,T6,
              nullptr, nullptr,nullptr,nullptr, HP, Z,Z, 0.f);              // mm pair
    c_pad_split<<<gPad, blk256, 0, stream>>>(fo, T1, T2);                   // fo pad pair
    k_mfma3<4,3><<<gNT, blk256, 0, stream>>>(T5,T6,T1,T2, S,nullptr,nullptr,
              nullptr, nullptr,maskf,nullptr, HP, sNT,sNT, 0.f);            // logits -> S
    k_colstats<<<dim3(Nd/64, Bd), dim3(1024), 0, stream>>>(S, cmaxv, csumv);
    k_rowstats<<<BN, blk256, 0, stream>>>(S, rmaxv, rsumv);
    c_prow_split<<<gNNel, blk256, 0, stream>>>(S, rmaxv, rsumv, Ph, Pl);    // p_row pair
    c_padT_split<<<gPadT, bT, 0, stream>>>(fo, T1, T2);                     // output^T pair
    k_mfma3<6,3><<<gBig, blk256, 0, stream>>>(Ph,Pl,T1,T2,
              sc1,nullptr,nullptr, nullptr, nullptr,maskf,cur,
              Nd, sNN,sT, 0.f);                                             // new_outs -> sc1
    c_pcolT_split<<<gPcolT, bT, 0, stream>>>(S, cmaxv, csumv, Ph, Pl);      // p_col^T pair
    c_padT_split<<<gPadT, bT, 0, stream>>>(cur, T3, T4);                    // outs^T pair (old)
    k_mfma3<7,3><<<gBig, blk256, 0, stream>>>(Ph,Pl,T3,T4,
              fo,nullptr,nullptr, nullptr, nullptr,maskf,nullptr,
              Nd, sNN,sT, 0.f);                                             // fo update

    float* t = cur; cur = sc1; sc1 = t;   // outs = new_outs
  }

  k_store<<<gBNH, blk256, 0, stream>>>(cur, out_outs);
}

// Round 9
// 1969.732 us; speedup vs baseline: 3.0561x; 1.0791x over previous
//
#include <hip/hip_runtime.h>
#include <hip/hip_bf16.h>
#include <math.h>

// Problem constants
#define Bd 8
#define Nd 1024
#define Hd 200
#define HP 224                      // Hd padded to multiple of 32
#define BN (Bd*Nd)                  // 8192
#define SZ_BNH ((size_t)BN*Hd)      // 1,638,400
#define SZ_BNN ((size_t)BN*Nd)      // 8,388,608
#define SZ_PAD ((size_t)BN*HP)      // 1,835,008

typedef __hip_bfloat16 bf16;
typedef __attribute__((ext_vector_type(8))) short bf16x8;   // 8 bf16 = 4 VGPRs (A/B frag)
typedef __attribute__((ext_vector_type(4))) float f32x4;    // C/D frag

__device__ __forceinline__ float bf2f(bf16 v){ return __bfloat162float(v); }
__device__ __forceinline__ bf16 f2bf(float v){ return __float2bfloat16(v); }
__device__ __forceinline__ short bfbits(bf16 v){ short s; __builtin_memcpy(&s, &v, 2); return s; }

#define MFMA16(a,b,c) __builtin_amdgcn_mfma_f32_16x16x32_bf16((a),(b),(c),0,0,0)

// ============================ prep (fp32) ============================
__global__ void k_prep_masks(const float* __restrict__ tm, float* __restrict__ maskf,
                             float* __restrict__ maskadd){
  int i = blockIdx.x*256 + threadIdx.x;
  if (i < BN){ float m = tm[i]; maskf[i] = m; maskadd[i] = (1.f - m) * -10000.f; }
}

__global__ void k_prep_adj(const float* __restrict__ a1, const float* __restrict__ a2,
                           float* __restrict__ adj_out, float* __restrict__ denom){
  int r = blockIdx.x;
  const size_t base = (size_t)r * Nd;
  int t = threadIdx.x;
  float s = 0.f;
  for (int m = t; m < Nd; m += 256){
    float a = a1[base+m] + a2[base+m];
    a = a >= 1.f ? 1.f : a;
    adj_out[base+m] = a;
    s += a;
  }
  __shared__ float red[256];
  red[t] = s; __syncthreads();
  for (int st = 128; st > 0; st >>= 1){ if (t < st) red[t] += red[t+st]; __syncthreads(); }
  if (t == 0) denom[r] = red[0] + 1e-07f;
}

__global__ void k_copy2(const float* __restrict__ x, float* __restrict__ o1,
                        float* __restrict__ o2){
  size_t i = (size_t)blockIdx.x*256 + threadIdx.x;
  if (i < SZ_BNH){ float v = x[i]; o1[i] = v; o2[i] = v; }
}

// ============================ split conversions ============================
__global__ void c_pad_split(const float* __restrict__ X, bf16* __restrict__ Oh,
                            bf16* __restrict__ Ol){
  size_t i = (size_t)blockIdx.x*256 + threadIdx.x;
  if (i >= SZ_PAD) return;
  int c = (int)(i % HP); size_t r = i / HP;
  float v = (c < Hd) ? X[r*Hd + c] : 0.f;
  bf16 h = f2bf(v);
  Oh[i] = h; Ol[i] = f2bf(v - bf2f(h));
}

__global__ void c_padT_split(const float* __restrict__ X, bf16* __restrict__ Oh,
                             bf16* __restrict__ Ol){
  __shared__ float t[32][33];
  int b = blockIdx.z, m0 = blockIdx.x*32, d0 = blockIdx.y*32;
  int tx = threadIdx.x, ty = threadIdx.y;          // block (32,8)
  for (int i = ty; i < 32; i += 8){
    int d = d0 + tx;
    t[i][tx] = (d < Hd) ? X[((size_t)b*Nd + m0+i)*Hd + d] : 0.f;
  }
  __syncthreads();
  for (int i = ty; i < 32; i += 8){
    size_t idx = (size_t)b*HP*Nd + (size_t)(d0+i)*Nd + m0 + tx;
    float v = t[tx][i];
    bf16 h = f2bf(v);
    Oh[idx] = h; Ol[idx] = f2bf(v - bf2f(h));
  }
}

__global__ void c_w_split(const float* __restrict__ W, bf16* __restrict__ Oh,
                          bf16* __restrict__ Ol){
  int i = blockIdx.x*256 + threadIdx.x;
  if (i >= HP*HP) return;
  int n = i / HP, k = i % HP;
  float v = (n < Hd && k < Hd) ? W[k*Hd + n] : 0.f;
  bf16 h = f2bf(v);
  Oh[i] = h; Ol[i] = f2bf(v - bf2f(h));
}

__global__ void c_cvt1024(const float* __restrict__ X, bf16* __restrict__ O){
  size_t i = (size_t)blockIdx.x*256 + threadIdx.x;
  if (i < SZ_BNN) O[i] = f2bf(X[i]);
}

__global__ void c_prow(const float* __restrict__ S, const float* __restrict__ rmax,
                       const float* __restrict__ rsum, bf16* __restrict__ P){
  size_t i = (size_t)blockIdx.x*256 + threadIdx.x;
  if (i >= SZ_BNN) return;
  size_t r = i >> 10;
  P[i] = f2bf(expf(S[i] - rmax[r]) * (1.f / rsum[r]));
}

__global__ void c_pcolT_split(const float* __restrict__ S, const float* __restrict__ cmax,
                              const float* __restrict__ csum, bf16* __restrict__ Ph,
                              bf16* __restrict__ Pl){
  __shared__ float t[32][33];
  int b = blockIdx.z, n0 = blockIdx.x*32, m0 = blockIdx.y*32;
  int tx = threadIdx.x, ty = threadIdx.y;          // block (32,8)
  for (int i = ty; i < 32; i += 8)
    t[i][tx] = S[(size_t)b*Nd*Nd + (size_t)(n0+i)*Nd + m0 + tx];
  __syncthreads();
  for (int i = ty; i < 32; i += 8){
    int m = m0 + i;
    float cm = cmax[b*Nd + m], ci = 1.f / csum[b*Nd + m];
    float p = expf(t[tx][i] - cm) * ci;
    size_t idx = (size_t)b*Nd*Nd + (size_t)m*Nd + n0 + tx;
    bf16 h = f2bf(p);
    Ph[idx] = h; Pl[idx] = f2bf(p - bf2f(h));
  }
}

// ============================ softmax stats (fp32) ============================
__global__ void k_rowstats(const float* __restrict__ S, float* __restrict__ rmax,
                           float* __restrict__ rsum){
  size_t r = blockIdx.x;
  const float* row = S + r*Nd;
  int t = threadIdx.x;
  __shared__ float red[256];
  float mx = -3.4e38f;
  for (int i = t; i < Nd; i += 256) mx = fmaxf(mx, row[i]);
  red[t] = mx; __syncthreads();
  for (int s = 128; s > 0; s >>= 1){ if (t < s) red[t] = fmaxf(red[t], red[t+s]); __syncthreads(); }
  mx = red[0]; __syncthreads();
  float sum = 0.f;
  for (int i = t; i < Nd; i += 256) sum += expf(row[i] - mx);
  red[t] = sum; __syncthreads();
  for (int s = 128; s > 0; s >>= 1){ if (t < s) red[t] += red[t+s]; __syncthreads(); }
  if (t == 0){ rmax[r] = mx; rsum[r] = red[0]; }
}

// Single-pass online column softmax stats. 1024 threads: 64 cols x 16 row-groups.
__global__ __launch_bounds__(1024)
void k_colstats(const float* __restrict__ S, float* __restrict__ cmax,
                float* __restrict__ csum){
  int b = blockIdx.y;
  int tx = threadIdx.x & 63, ty = threadIdx.x >> 6;   // ty in 0..15
  int m = blockIdx.x*64 + tx;
  const float* Sbp = S + (size_t)b*Nd*Nd + m;
  float mx = -3.4e38f, sm = 0.f;
  for (int n = ty; n < Nd; n += 16){
    float x = Sbp[(size_t)n*Nd];
    if (x > mx){ sm = sm * expf(mx - x) + 1.f; mx = x; }
    else        sm += expf(x - mx);
  }
  __shared__ float smx[16][64], ssm[16][64];
  smx[ty][tx] = mx; ssm[ty][tx] = sm;
  __syncthreads();
  for (int st = 8; st > 0; st >>= 1){
    if (ty < st){
      float m1 = smx[ty][tx],    s1 = ssm[ty][tx];
      float m2 = smx[ty+st][tx], s2 = ssm[ty+st][tx];
      float M = fmaxf(m1, m2);
      smx[ty][tx] = M;
      ssm[ty][tx] = s1*expf(m1 - M) + s2*expf(m2 - M);
    }
    __syncthreads();
  }
  if (ty == 0){ cmax[b*Nd + m] = smx[0][tx]; csum[b*Nd + m] = ssm[0][tx]; }
}

// ============================ residual + layernorm ============================
__global__ void k_add_ln(const float* __restrict__ X, const float* __restrict__ R,
                         const float* __restrict__ g, const float* __restrict__ bb,
                         float* __restrict__ Y){
  int r = blockIdx.x, t = threadIdx.x;
  __shared__ float red[256];
  bool act = t < Hd;
  float v = 0.f;
  if (act) v = X[(size_t)r*Hd + t] + R[(size_t)r*Hd + t];
  red[t] = act ? v : 0.f; __syncthreads();
  for (int s = 128; s > 0; s >>= 1){ if (t < s) red[t] += red[t+s]; __syncthreads(); }
  float mu = red[0] * (1.f/Hd); __syncthreads();
  float d = act ? (v - mu) : 0.f;
  red[t] = d*d; __syncthreads();
  for (int s = 128; s > 0; s >>= 1){ if (t < s) red[t] += red[t+s]; __syncthreads(); }
  float var = red[0] * (1.f/Hd);
  if (act){
    float rs = 1.f / sqrtf(var + 1e-20f);
    Y[(size_t)r*Hd + t] = (v - mu) * rs * g[t] + bb[t];
  }
}

__global__ void k_store(const float* __restrict__ X, float* __restrict__ O){
  size_t i = (size_t)blockIdx.x*256 + threadIdx.x;
  if (i < SZ_BNH) O[i] = X[i];
}

// ============================ split-precision MFMA GEMM, 2x4 tiles/wave =========
// D[m][n] = sum_k A[m][k]*B[n][k] (NT) with Dekker split operands.
// TERMS=3: Ah*Bh + Ah*Bl + Al*Bh. TERMS=2: Ah*(Bh+Bl), A exact single buffer.
// Wave = 32 rows x 64 cols (2x4 MFMA tiles); block = 4 waves stacked in M (128 rows).
// Requires M%128==0. N may exceed logical width (OOB B-tiles read in-workspace garbage,
// discarded by col<Hd epilogue guards).
// EPI: 0 fp32 Y=acc+bias  1 +gelu  2 split-bf16pad out (Ybh/Ybl)
//      3 S=acc*scale+maskadd[col]  4 S=acc+pairmask  5 Y+=relu(acc/denom[row])
//      7 Y=acc*maskf[row]+Y
template<int EPI, int TERMS>
__global__ __launch_bounds__(256)
void k_mfma3(const bf16* __restrict__ Ah, const bf16* __restrict__ Al,
             const bf16* __restrict__ Bh, const bf16* __restrict__ Bl,
             float* __restrict__ Y, bf16* __restrict__ Ybh, bf16* __restrict__ Ybl,
             const float* __restrict__ bias, const float* __restrict__ e0,
             const float* __restrict__ e1, const float* __restrict__ R,
             int Kp, size_t sAb, size_t sBb, float scale)
{
  int b = blockIdx.z;
  int wave = threadIdx.x >> 6, lane = threadIdx.x & 63;
  int r0 = (blockIdx.y*4 + wave)*32;      // 32 rows per wave
  int c0 = blockIdx.x*64;                 // 64 cols per wave
  int lm = lane & 15, lq = lane >> 4;
  size_t a0 = (size_t)b*sAb + (size_t)(r0+lm)*Kp + lq*8;
  size_t bo = (size_t)b*sBb + (size_t)(c0+lm)*Kp + lq*8;

  f32x4 acc[2][4] = {};
  for (int k = 0; k < Kp; k += 32){
    bf16x8 ah[2], bh[4], bl[4];
    #pragma unroll
    for (int i = 0; i < 2; i++) ah[i] = *(const bf16x8*)(Ah + a0 + (size_t)(i*16)*Kp + k);
    #pragma unroll
    for (int j = 0; j < 4; j++){
      bh[j] = *(const bf16x8*)(Bh + bo + (size_t)(j*16)*Kp + k);
      bl[j] = *(const bf16x8*)(Bl + bo + (size_t)(j*16)*Kp + k);
    }
    #pragma unroll
    for (int i = 0; i < 2; i++)
      #pragma unroll
      for (int j = 0; j < 4; j++) acc[i][j] = MFMA16(ah[i], bh[j], acc[i][j]);
    #pragma unroll
    for (int i = 0; i < 2; i++)
      #pragma unroll
      for (int j = 0; j < 4; j++) acc[i][j] = MFMA16(ah[i], bl[j], acc[i][j]);
    if (TERMS >= 3){
      bf16x8 al[2];
      #pragma unroll
      for (int i = 0; i < 2; i++) al[i] = *(const bf16x8*)(Al + a0 + (size_t)(i*16)*Kp + k);
      #pragma unroll
      for (int i = 0; i < 2; i++)
        #pragma unroll
        for (int j = 0; j < 4; j++) acc[i][j] = MFMA16(al[i], bh[j], acc[i][j]);
    }
  }

  #pragma unroll
  for (int i = 0; i < 2; i++){
    #pragma unroll
    for (int j = 0; j < 4; j++){
      int col = c0 + j*16 + lm;
      int rbase = r0 + i*16 + lq*4;
      #pragma unroll
      for (int r = 0; r < 4; r++){
        int row = rbase + r;
        size_t rowg = (size_t)b*Nd + row;
        float v = acc[i][j][r];
        if (EPI == 0 || EPI == 1){
          if (col < Hd){
            v += bias ? bias[col] : 0.f;
            if (EPI == 1) v = 0.5f*v*(1.f + erff(v*0.7071067811865476f));
            Y[rowg*Hd + col] = v;
          }
        } else if (EPI == 2){
          if (col < HP){
            float o = (col < Hd) ? v + (bias ? bias[col] : 0.f) : 0.f;
            bf16 h = f2bf(o);
            Ybh[rowg*HP + col] = h;
            Ybl[rowg*HP + col] = f2bf(o - bf2f(h));
          }
        } else if (EPI == 3){
          Y[rowg*Nd + col] = v*scale + e0[b*Nd + col];
        } else if (EPI == 4){
          Y[rowg*Nd + col] = v + (1.f - e1[b*Nd+row]*e1[b*Nd+col])*(-10000.f);
        } else if (EPI == 5){
          if (col < Hd){
            float u = v / e0[b*Nd+row]; u = u > 0.f ? u : 0.f;
            Y[rowg*Hd + col] += u;
          }
        } else if (EPI == 7){
          if (col < Hd) Y[rowg*Hd+col] = v*e1[b*Nd+row] + Y[rowg*Hd+col];
        }
      }
    }
  }
}

// ============================ fused p_row mix (new_outs) ============================
// Y[b,n,d] = (sum_m exp(S[b,n,m]-rmax)/rsum * B[d,m]) * maskf[b,n] + R[b,n,d]
// A-frags built on the fly from fp32 S (identical math to c_prow_split + k_mfma3<.,3>).
__global__ __launch_bounds__(256)
void k_mix_prow(const float* __restrict__ S, const float* __restrict__ rmax,
                const float* __restrict__ rsum,
                const bf16* __restrict__ Bh, const bf16* __restrict__ Bl,
                float* __restrict__ Y, const float* __restrict__ maskf,
                const float* __restrict__ R)
{
  int b = blockIdx.z;
  int wave = threadIdx.x >> 6, lane = threadIdx.x & 63;
  int r0 = (blockIdx.y*4 + wave)*32;
  int c0 = blockIdx.x*64;
  int lm = lane & 15, lq = lane >> 4;
  const float* pS0 = S + (size_t)b*Nd*Nd + (size_t)(r0+lm)*Nd + lq*8;
  const float* pS1 = pS0 + (size_t)16*Nd;
  size_t bo = (size_t)b*((size_t)HP*Nd) + (size_t)(c0+lm)*Nd + lq*8;
  float rm0 = rmax[b*Nd + r0+lm],      ri0 = 1.f / rsum[b*Nd + r0+lm];
  float rm1 = rmax[b*Nd + r0+16+lm],   ri1 = 1.f / rsum[b*Nd + r0+16+lm];

  f32x4 acc[2][4] = {};
  for (int k = 0; k < Nd; k += 32){
    bf16x8 ah[2], al[2], bh[4], bl[4];
    #pragma unroll
    for (int j = 0; j < 4; j++){
      bh[j] = *(const bf16x8*)(Bh + bo + (size_t)(j*16)*Nd + k);
      bl[j] = *(const bf16x8*)(Bl + bo + (size_t)(j*16)*Nd + k);
    }
    #pragma unroll
    for (int j = 0; j < 8; j++){
      float p0 = expf(pS0[k+j] - rm0) * ri0;
      bf16 h0 = f2bf(p0);
      ah[0][j] = bfbits(h0); al[0][j] = bfbits(f2bf(p0 - bf2f(h0)));
      float p1 = expf(pS1[k+j] - rm1) * ri1;
      bf16 h1 = f2bf(p1);
      ah[1][j] = bfbits(h1); al[1][j] = bfbits(f2bf(p1 - bf2f(h1)));
    }
    #pragma unroll
    for (int i = 0; i < 2; i++)
      #pragma unroll
      for (int j = 0; j < 4; j++) acc[i][j] = MFMA16(ah[i], bh[j], acc[i][j]);
    #pragma unroll
    for (int i = 0; i < 2; i++)
      #pragma unroll
      for (int j = 0; j < 4; j++) acc[i][j] = MFMA16(ah[i], bl[j], acc[i][j]);
    #pragma unroll
    for (int i = 0; i < 2; i++)
      #pragma unroll
      for (int j = 0; j < 4; j++) acc[i][j] = MFMA16(al[i], bh[j], acc[i][j]);
  }

  #pragma unroll
  for (int i = 0; i < 2; i++){
    #pragma unroll
    for (int j = 0; j < 4; j++){
      int col = c0 + j*16 + lm;
      if (col >= Hd) continue;
      int rbase = r0 + i*16 + lq*4;
      #pragma unroll
      for (int r = 0; r < 4; r++){
        int row = rbase + r;
        size_t rowg = (size_t)b*Nd + row;
        Y[rowg*Hd + col] = acc[i][j][r]*maskf[b*Nd+row] + R[rowg*Hd + col];
      }
    }
  }
}

// ============================ host launch ============================
static inline char* carve(char*& p, size_t bytes){
  char* r = p;
  p += (bytes + 511) & ~(size_t)511;
  return r;
}

extern "C" void kernel_launch(void* const* d_in, const int* in_sizes, int n_in,
                              void* d_out, int out_size, void* d_ws, size_t ws_size,
                              hipStream_t stream){
  (void)in_sizes; (void)n_in; (void)out_size; (void)ws_size;
  const float* text     = (const float*)d_in[0];
  const float* adj1     = (const float*)d_in[1];
  const float* adj2     = (const float*)d_in[2];
  const float* textmask = (const float*)d_in[5];
  const float* gcn_w    = (const float*)d_in[6];
  const float* mut_w    = (const float*)d_in[7];
  const float* qw = (const float*)d_in[8],  *qb = (const float*)d_in[9];
  const float* kw = (const float*)d_in[10], *kb = (const float*)d_in[11];
  const float* vw = (const float*)d_in[12], *vb = (const float*)d_in[13];
  const float* aow= (const float*)d_in[14], *aob= (const float*)d_in[15];
  const float* g1 = (const float*)d_in[16], *b1 = (const float*)d_in[17];
  const float* iw = (const float*)d_in[18], *ib = (const float*)d_in[19];
  const float* ow = (const float*)d_in[20], *ob = (const float*)d_in[21];
  const float* g2 = (const float*)d_in[22], *b2 = (const float*)d_in[23];

  float* out_outs = (float*)d_out;
  float* out_adj  = out_outs + SZ_BNH;

  // ---- workspace carve (~109 MB). out_outs doubles as fp32 scratch sc2. ----
  char* p = (char*)d_ws;
  float* cur  = (float*)carve(p, SZ_BNH*4);
  float* sc1  = (float*)carve(p, SZ_BNH*4);
  float* fo   = (float*)carve(p, SZ_BNH*4);
  float* S    = (float*)carve(p, SZ_BNN*4);           // fp32 scores / logits
  bf16*  Rb   = (bf16*)carve(p, SZ_BNN*2*2);          // big bf16 region (33.6 MB)
  bf16*  T1   = (bf16*)carve(p, SZ_PAD*2);
  bf16*  T2   = (bf16*)carve(p, SZ_PAD*2);
  bf16*  T3   = (bf16*)carve(p, SZ_PAD*2);
  bf16*  T4   = (bf16*)carve(p, SZ_PAD*2);
  bf16*  T5   = (bf16*)carve(p, SZ_PAD*2);
  bf16*  T6   = (bf16*)carve(p, SZ_PAD*2);
  bf16*  Wh   = (bf16*)carve(p, (size_t)HP*HP*2);
  bf16*  Wl   = (bf16*)carve(p, (size_t)HP*HP*2);
  float* denom   = (float*)carve(p, BN*4);
  float* maskf   = (float*)carve(p, BN*4);
  float* maskadd = (float*)carve(p, BN*4);
  float* rmaxv   = (float*)carve(p, BN*4);
  float* rsumv   = (float*)carve(p, BN*4);
  float* cmaxv   = (float*)carve(p, BN*4);
  float* csumv   = (float*)carve(p, BN*4);

  float* sc2 = out_outs;          // fp32 scratch; overwritten by final k_store
  bf16* attnP = Rb;               // phases: attnP -> adjb -> Ph/Pl (sequential)
  bf16* adjb  = Rb;
  bf16* Ph    = Rb;
  bf16* Pl    = Rb + SZ_BNN;

  const size_t sNT = (size_t)Nd*HP;     // batch stride, [1024][224]
  const size_t sT  = (size_t)HP*Nd;     // batch stride, [224][1024]
  const size_t sNN = (size_t)Nd*Nd;     // batch stride, [1024][1024]

  dim3 blk256(256);
  dim3 gPad((unsigned)((SZ_PAD+255)/256));
  dim3 gPadT(32, 7, Bd), bT(32, 8);
  dim3 gPcolT(32, 32, Bd);
  dim3 gW((HP*HP+255)/256);
  dim3 gNNel((unsigned)((SZ_BNN+255)/256));
  dim3 gBNH((unsigned)((SZ_BNH+255)/256));
  // GEMM grids: wave = 32 rows x 64 cols, block = 128 rows x 64 cols
  dim3 gSm(4, 64, 1);        // small GEMM: 8192x224(pad 256), K=HP
  dim3 gNT(16, 8, Bd);       // scores/logits: 1024x1024, K=HP
  dim3 gBig(4, 8, Bd);       // big mixes: 1024x224(pad 256), K=1024
  const float inv_sqrt_h = 0.07071067811865475f;  // 1/sqrt(200)
  const size_t Z = 0;

  k_prep_masks<<<(BN+255)/256, blk256, 0, stream>>>(textmask, maskf, maskadd);
  k_prep_adj<<<BN, blk256, 0, stream>>>(adj1, adj2, out_adj, denom);
  k_copy2<<<gBNH, blk256, 0, stream>>>(text, cur, fo);

  for (int i = 0; i < 3; i++){
    const float *qwi = qw + i*Hd*Hd, *qbi = qb + i*Hd;
    const float *kwi = kw + i*Hd*Hd, *kbi = kb + i*Hd;
    const float *vwi = vw + i*Hd*Hd, *vbi = vb + i*Hd;
    const float *aowi= aow+ i*Hd*Hd, *aobi= aob+ i*Hd;
    const float *g1i = g1 + i*Hd,    *b1i = b1 + i*Hd;
    const float *iwi = iw + i*Hd*Hd, *ibi = ib + i*Hd;
    const float *owi = ow + i*Hd*Hd, *obi = ob + i*Hd;
    const float *g2i = g2 + i*Hd,    *b2i = b2 + i*Hd;

    // ================= BERT layer: cur -> cur =================
    c_pad_split<<<gPad, blk256, 0, stream>>>(cur, T1, T2);                  // cur pair
    c_w_split<<<gW, blk256, 0, stream>>>(qwi, Wh, Wl);
    k_mfma3<2,3><<<gSm, blk256, 0, stream>>>(T1,T2,Wh,Wl, nullptr,T3,T4,
              qbi, nullptr,nullptr,nullptr, HP, Z,Z, 0.f);                  // Q pair
    c_w_split<<<gW, blk256, 0, stream>>>(kwi, Wh, Wl);
    k_mfma3<2,3><<<gSm, blk256, 0, stream>>>(T1,T2,Wh,Wl, nullptr,T5,T6,
              kbi, nullptr,nullptr,nullptr, HP, Z,Z, 0.f);                  // K pair
    k_mfma3<3,3><<<gNT, blk256, 0, stream>>>(T3,T4,T5,T6, S,nullptr,nullptr,
              nullptr, maskadd,nullptr,nullptr, HP, sNT,sNT, inv_sqrt_h);   // scores
    c_w_split<<<gW, blk256, 0, stream>>>(vwi, Wh, Wl);
    k_mfma3<0,3><<<gSm, blk256, 0, stream>>>(T1,T2,Wh,Wl, sc1,nullptr,nullptr,
              vbi, nullptr,nullptr,nullptr, HP, Z,Z, 0.f);                  // V fp32
    k_rowstats<<<BN, blk256, 0, stream>>>(S, rmaxv, rsumv);
    c_prow<<<gNNel, blk256, 0, stream>>>(S, rmaxv, rsumv, attnP);           // probs (single)
    c_padT_split<<<gPadT, bT, 0, stream>>>(sc1, T1, T2);                    // V^T pair
    k_mfma3<0,2><<<gBig, blk256, 0, stream>>>(attnP,nullptr,T1,T2,
              sc2,nullptr,nullptr, nullptr, nullptr,nullptr,nullptr,
              Nd, sNN,sT, 0.f);                                             // ctx
    c_pad_split<<<gPad, blk256, 0, stream>>>(sc2, T3, T4);
    c_w_split<<<gW, blk256, 0, stream>>>(aowi, Wh, Wl);
    k_mfma3<0,3><<<gSm, blk256, 0, stream>>>(T3,T4,Wh,Wl, sc1,nullptr,nullptr,
              aobi, nullptr,nullptr,nullptr, HP, Z,Z, 0.f);                 // ao_out
    k_add_ln<<<BN, blk256, 0, stream>>>(sc1, cur, g1i, b1i, sc2);           // attn -> sc2
    c_pad_split<<<gPad, blk256, 0, stream>>>(sc2, T1, T2);
    c_w_split<<<gW, blk256, 0, stream>>>(iwi, Wh, Wl);
    k_mfma3<1,3><<<gSm, blk256, 0, stream>>>(T1,T2,Wh,Wl, sc1,nullptr,nullptr,
              ibi, nullptr,nullptr,nullptr, HP, Z,Z, 0.f);                  // gelu(inter)
    c_pad_split<<<gPad, blk256, 0, stream>>>(sc1, T3, T4);
    c_w_split<<<gW, blk256, 0, stream>>>(owi, Wh, Wl);
    k_mfma3<0,3><<<gSm, blk256, 0, stream>>>(T3,T4,Wh,Wl, cur,nullptr,nullptr,
              obi, nullptr,nullptr,nullptr, HP, Z,Z, 0.f);                  // ow_out -> cur
    k_add_ln<<<BN, blk256, 0, stream>>>(cur, sc2, g2i, b2i, cur);           // bert out

    // ================= GCN on fo =================
    c_pad_split<<<gPad, blk256, 0, stream>>>(fo, T1, T2);
    c_w_split<<<gW, blk256, 0, stream>>>(gcn_w, Wh, Wl);
    k_mfma3<0,3><<<gSm, blk256, 0, stream>>>(T1,T2,Wh,Wl, sc1,nullptr,nullptr,
              nullptr, nullptr,nullptr,nullptr, HP, Z,Z, 0.f);              // teout
    c_padT_split<<<gPadT, bT, 0, stream>>>(sc1, T3, T4);                    // teout^T pair
    c_cvt1024<<<gNNel, blk256, 0, stream>>>(out_adj, adjb);                 // adj bf16 exact
    k_mfma3<5,2><<<gBig, blk256, 0, stream>>>(adjb,nullptr,T3,T4,
              fo,nullptr,nullptr, nullptr, denom,nullptr,nullptr,
              Nd, sNN,sT, 0.f);                                             // fo += relu(./denom)

    // ================= self-alignment =================
    c_pad_split<<<gPad, blk256, 0, stream>>>(cur, T1, T2);
    c_w_split<<<gW, blk256, 0, stream>>>(mut_w, Wh, Wl);
    k_mfma3<2,3><<<gSm, blk256, 0, stream>>>(T1,T2,Wh,Wl, nullptr,T5,T6,
              nullptr, nullptr,nullptr,nullptr, HP, Z,Z, 0.f);              // mm pair
    c_pad_split<<<gPad, blk256, 0, stream>>>(fo, T1, T2);                   // fo pad pair
    k_mfma3<4,3><<<gNT, blk256, 0, stream>>>(T5,T6,T1,T2, S,nullptr,nullptr,
              nullptr, nullptr,maskf,nullptr, HP, sNT,sNT, 0.f);            // logits -> S
    k_colstats<<<dim3(Nd/64, Bd), dim3(1024), 0, stream>>>(S, cmaxv, csumv);
    k_rowstats<<<BN, blk256, 0, stream>>>(S, rmaxv, rsumv);
    c_padT_split<<<gPadT, bT, 0, stream>>>(fo, T1, T2);                     // output^T pair
    k_mix_prow<<<gBig, blk256, 0, stream>>>(S, rmaxv, rsumv, T1, T2,
              sc1, maskf, cur);                                             // new_outs -> sc1 (fused)
    c_pcolT_split<<<gPcolT, bT, 0, stream>>>(S, cmaxv, csumv, Ph, Pl);      // p_col^T pair
    c_padT_split<<<gPadT, bT, 0, stream>>>(cur, T3, T4);                    // outs^T pair (old)
    k_mfma3<7,3><<<gBig, blk256, 0, stream>>>(Ph,Pl,T3,T4,
              fo,nullptr,nullptr, nullptr, nullptr,maskf,nullptr,
              Nd, sNN,sT, 0.f);                                             // fo update

    float* t = cur; cur = sc1; sc1 = t;   // outs = new_outs
  }

  k_store<<<gBNH, blk256, 0, stream>>>(cur, out_outs);
}

// Round 10
// 1938.152 us; speedup vs baseline: 3.1059x; 1.0163x over previous
//
#include <hip/hip_runtime.h>
#include <hip/hip_bf16.h>
#include <math.h>

// Problem constants
#define Bd 8
#define Nd 1024
#define Hd 200
#define HP 224                      // Hd padded to multiple of 32
#define BN (Bd*Nd)                  // 8192
#define SZ_BNH ((size_t)BN*Hd)      // 1,638,400
#define SZ_BNN ((size_t)BN*Nd)      // 8,388,608
#define SZ_PAD ((size_t)BN*HP)      // 1,835,008

typedef __hip_bfloat16 bf16;
typedef __attribute__((ext_vector_type(8))) short bf16x8;   // 8 bf16 = 4 VGPRs (A/B frag)
typedef __attribute__((ext_vector_type(4))) float f32x4;    // C/D frag

__device__ __forceinline__ float bf2f(bf16 v){ return __bfloat162float(v); }
__device__ __forceinline__ bf16 f2bf(float v){ return __float2bfloat16(v); }
__device__ __forceinline__ short bfbits(bf16 v){ short s; __builtin_memcpy(&s, &v, 2); return s; }

#define MFMA16(a,b,c) __builtin_amdgcn_mfma_f32_16x16x32_bf16((a),(b),(c),0,0,0)

// ============================ prep (fp32) ============================
__global__ void k_prep_masks(const float* __restrict__ tm, float* __restrict__ maskf,
                             float* __restrict__ maskadd){
  int i = blockIdx.x*256 + threadIdx.x;
  if (i < BN){ float m = tm[i]; maskf[i] = m; maskadd[i] = (1.f - m) * -10000.f; }
}

__global__ void k_prep_adj(const float* __restrict__ a1, const float* __restrict__ a2,
                           float* __restrict__ adj_out, float* __restrict__ denom){
  int r = blockIdx.x;
  const size_t base = (size_t)r * Nd;
  int t = threadIdx.x;
  float s = 0.f;
  for (int m = t; m < Nd; m += 256){
    float a = a1[base+m] + a2[base+m];
    a = a >= 1.f ? 1.f : a;
    adj_out[base+m] = a;
    s += a;
  }
  __shared__ float red[256];
  red[t] = s; __syncthreads();
  for (int st = 128; st > 0; st >>= 1){ if (t < st) red[t] += red[t+st]; __syncthreads(); }
  if (t == 0) denom[r] = red[0] + 1e-07f;
}

__global__ void k_copy2(const float* __restrict__ x, float* __restrict__ o1,
                        float* __restrict__ o2){
  size_t i = (size_t)blockIdx.x*256 + threadIdx.x;
  if (i < SZ_BNH){ float v = x[i]; o1[i] = v; o2[i] = v; }
}

// ============================ split conversions ============================
__global__ void c_pad_split(const float* __restrict__ X, bf16* __restrict__ Oh,
                            bf16* __restrict__ Ol){
  size_t i = (size_t)blockIdx.x*256 + threadIdx.x;
  if (i >= SZ_PAD) return;
  int c = (int)(i % HP); size_t r = i / HP;
  float v = (c < Hd) ? X[r*Hd + c] : 0.f;
  bf16 h = f2bf(v);
  Oh[i] = h; Ol[i] = f2bf(v - bf2f(h));
}

__global__ void c_padT_split(const float* __restrict__ X, bf16* __restrict__ Oh,
                             bf16* __restrict__ Ol){
  __shared__ float t[32][33];
  int b = blockIdx.z, m0 = blockIdx.x*32, d0 = blockIdx.y*32;
  int tx = threadIdx.x, ty = threadIdx.y;          // block (32,8)
  for (int i = ty; i < 32; i += 8){
    int d = d0 + tx;
    t[i][tx] = (d < Hd) ? X[((size_t)b*Nd + m0+i)*Hd + d] : 0.f;
  }
  __syncthreads();
  for (int i = ty; i < 32; i += 8){
    size_t idx = (size_t)b*HP*Nd + (size_t)(d0+i)*Nd + m0 + tx;
    float v = t[tx][i];
    bf16 h = f2bf(v);
    Oh[idx] = h; Ol[idx] = f2bf(v - bf2f(h));
  }
}

__global__ void c_w_split(const float* __restrict__ W, bf16* __restrict__ Oh,
                          bf16* __restrict__ Ol){
  int i = blockIdx.x*256 + threadIdx.x;
  if (i >= HP*HP) return;
  int n = i / HP, k = i % HP;
  float v = (n < Hd && k < Hd) ? W[k*Hd + n] : 0.f;
  bf16 h = f2bf(v);
  Oh[i] = h; Ol[i] = f2bf(v - bf2f(h));
}

__global__ void c_cvt1024(const float* __restrict__ X, bf16* __restrict__ O){
  size_t i = (size_t)blockIdx.x*256 + threadIdx.x;
  if (i < SZ_BNN) O[i] = f2bf(X[i]);
}

__global__ void c_pcolT_split(const float* __restrict__ S, const float* __restrict__ cmax,
                              const float* __restrict__ csum, bf16* __restrict__ Ph,
                              bf16* __restrict__ Pl){
  __shared__ float t[32][33];
  int b = blockIdx.z, n0 = blockIdx.x*32, m0 = blockIdx.y*32;
  int tx = threadIdx.x, ty = threadIdx.y;          // block (32,8)
  for (int i = ty; i < 32; i += 8)
    t[i][tx] = S[(size_t)b*Nd*Nd + (size_t)(n0+i)*Nd + m0 + tx];
  __syncthreads();
  for (int i = ty; i < 32; i += 8){
    int m = m0 + i;
    float cm = cmax[b*Nd + m], ci = 1.f / csum[b*Nd + m];
    float p = expf(t[tx][i] - cm) * ci;
    size_t idx = (size_t)b*Nd*Nd + (size_t)m*Nd + n0 + tx;
    bf16 h = f2bf(p);
    Ph[idx] = h; Pl[idx] = f2bf(p - bf2f(h));
  }
}

// ============================ softmax stats (fp32) ============================
__global__ void k_rowstats(const float* __restrict__ S, float* __restrict__ rmax,
                           float* __restrict__ rsum){
  size_t r = blockIdx.x;
  const float* row = S + r*Nd;
  int t = threadIdx.x;
  __shared__ float red[256];
  float mx = -3.4e38f;
  for (int i = t; i < Nd; i += 256) mx = fmaxf(mx, row[i]);
  red[t] = mx; __syncthreads();
  for (int s = 128; s > 0; s >>= 1){ if (t < s) red[t] = fmaxf(red[t], red[t+s]); __syncthreads(); }
  mx = red[0]; __syncthreads();
  float sum = 0.f;
  for (int i = t; i < Nd; i += 256) sum += expf(row[i] - mx);
  red[t] = sum; __syncthreads();
  for (int s = 128; s > 0; s >>= 1){ if (t < s) red[t] += red[t+s]; __syncthreads(); }
  if (t == 0){ rmax[r] = mx; rsum[r] = red[0]; }
}

// Single-pass online column softmax stats. 1024 threads: 64 cols x 16 row-groups.
__global__ __launch_bounds__(1024)
void k_colstats(const float* __restrict__ S, float* __restrict__ cmax,
                float* __restrict__ csum){
  int b = blockIdx.y;
  int tx = threadIdx.x & 63, ty = threadIdx.x >> 6;   // ty in 0..15
  int m = blockIdx.x*64 + tx;
  const float* Sbp = S + (size_t)b*Nd*Nd + m;
  float mx = -3.4e38f, sm = 0.f;
  for (int n = ty; n < Nd; n += 16){
    float x = Sbp[(size_t)n*Nd];
    if (x > mx){ sm = sm * expf(mx - x) + 1.f; mx = x; }
    else        sm += expf(x - mx);
  }
  __shared__ float smx[16][64], ssm[16][64];
  smx[ty][tx] = mx; ssm[ty][tx] = sm;
  __syncthreads();
  for (int st = 8; st > 0; st >>= 1){
    if (ty < st){
      float m1 = smx[ty][tx],    s1 = ssm[ty][tx];
      float m2 = smx[ty+st][tx], s2 = ssm[ty+st][tx];
      float M = fmaxf(m1, m2);
      smx[ty][tx] = M;
      ssm[ty][tx] = s1*expf(m1 - M) + s2*expf(m2 - M);
    }
    __syncthreads();
  }
  if (ty == 0){ cmax[b*Nd + m] = smx[0][tx]; csum[b*Nd + m] = ssm[0][tx]; }
}

// ============================ residual + layernorm ============================
__global__ void k_add_ln(const float* __restrict__ X, const float* __restrict__ R,
                         const float* __restrict__ g, const float* __restrict__ bb,
                         float* __restrict__ Y){
  int r = blockIdx.x, t = threadIdx.x;
  __shared__ float red[256];
  bool act = t < Hd;
  float v = 0.f;
  if (act) v = X[(size_t)r*Hd + t] + R[(size_t)r*Hd + t];
  red[t] = act ? v : 0.f; __syncthreads();
  for (int s = 128; s > 0; s >>= 1){ if (t < s) red[t] += red[t+s]; __syncthreads(); }
  float mu = red[0] * (1.f/Hd); __syncthreads();
  float d = act ? (v - mu) : 0.f;
  red[t] = d*d; __syncthreads();
  for (int s = 128; s > 0; s >>= 1){ if (t < s) red[t] += red[t+s]; __syncthreads(); }
  float var = red[0] * (1.f/Hd);
  if (act){
    float rs = 1.f / sqrtf(var + 1e-20f);
    Y[(size_t)r*Hd + t] = (v - mu) * rs * g[t] + bb[t];
  }
}

__global__ void k_store(const float* __restrict__ X, float* __restrict__ O){
  size_t i = (size_t)blockIdx.x*256 + threadIdx.x;
  if (i < SZ_BNH) O[i] = X[i];
}

// ============================ split-precision MFMA GEMM (no split-K) ============
// D[m][n] = sum_k A[m][k]*B[n][k] (NT), Dekker split. RI row-tiles x 4 col-tiles/wave.
// Block = 4 waves stacked in M. EPI: 0 fp32 Y=acc+bias  1 +gelu  2 split-bf16pad out
// 3 S=acc*scale+maskadd[col]  4 S=acc+pairmask
template<int EPI, int TERMS, int RI>
__global__ __launch_bounds__(256)
void k_mfma3(const bf16* __restrict__ Ah, const bf16* __restrict__ Al,
             const bf16* __restrict__ Bh, const bf16* __restrict__ Bl,
             float* __restrict__ Y, bf16* __restrict__ Ybh, bf16* __restrict__ Ybl,
             const float* __restrict__ bias, const float* __restrict__ e0,
             const float* __restrict__ e1,
             int Kp, size_t sAb, size_t sBb, float scale)
{
  int b = blockIdx.z;
  int wave = threadIdx.x >> 6, lane = threadIdx.x & 63;
  int r0 = (blockIdx.y*4 + wave)*(RI*16);
  int c0 = blockIdx.x*64;
  int lm = lane & 15, lq = lane >> 4;
  size_t a0 = (size_t)b*sAb + (size_t)(r0+lm)*Kp + lq*8;
  size_t bo = (size_t)b*sBb + (size_t)(c0+lm)*Kp + lq*8;

  f32x4 acc[RI][4] = {};
  for (int k = 0; k < Kp; k += 32){
    bf16x8 ah[RI], bh[4], bl[4];
    #pragma unroll
    for (int i = 0; i < RI; i++) ah[i] = *(const bf16x8*)(Ah + a0 + (size_t)(i*16)*Kp + k);
    #pragma unroll
    for (int j = 0; j < 4; j++){
      bh[j] = *(const bf16x8*)(Bh + bo + (size_t)(j*16)*Kp + k);
      bl[j] = *(const bf16x8*)(Bl + bo + (size_t)(j*16)*Kp + k);
    }
    #pragma unroll
    for (int i = 0; i < RI; i++)
      #pragma unroll
      for (int j = 0; j < 4; j++) acc[i][j] = MFMA16(ah[i], bh[j], acc[i][j]);
    #pragma unroll
    for (int i = 0; i < RI; i++)
      #pragma unroll
      for (int j = 0; j < 4; j++) acc[i][j] = MFMA16(ah[i], bl[j], acc[i][j]);
    if (TERMS >= 3){
      bf16x8 al[RI];
      #pragma unroll
      for (int i = 0; i < RI; i++) al[i] = *(const bf16x8*)(Al + a0 + (size_t)(i*16)*Kp + k);
      #pragma unroll
      for (int i = 0; i < RI; i++)
        #pragma unroll
        for (int j = 0; j < 4; j++) acc[i][j] = MFMA16(al[i], bh[j], acc[i][j]);
    }
  }

  #pragma unroll
  for (int i = 0; i < RI; i++){
    #pragma unroll
    for (int j = 0; j < 4; j++){
      int col = c0 + j*16 + lm;
      int rbase = r0 + i*16 + lq*4;
      #pragma unroll
      for (int r = 0; r < 4; r++){
        int row = rbase + r;
        size_t rowg = (size_t)b*Nd + row;
        float v = acc[i][j][r];
        if (EPI == 0 || EPI == 1){
          if (col < Hd){
            v += bias ? bias[col] : 0.f;
            if (EPI == 1) v = 0.5f*v*(1.f + erff(v*0.7071067811865476f));
            Y[rowg*Hd + col] = v;
          }
        } else if (EPI == 2){
          if (col < HP){
            float o = (col < Hd) ? v + (bias ? bias[col] : 0.f) : 0.f;
            bf16 h = f2bf(o);
            Ybh[rowg*HP + col] = h;
            Ybl[rowg*HP + col] = f2bf(o - bf2f(h));
          }
        } else if (EPI == 3){
          Y[rowg*Nd + col] = v*scale + e0[b*Nd + col];
        } else if (EPI == 4){
          Y[rowg*Nd + col] = v + (1.f - e1[b*Nd+row]*e1[b*Nd+col])*(-10000.f);
        }
      }
    }
  }
}

// ============================ split-K=4 MFMA GEMM (K=1024 mixes) ================
// Block = one 32x64 tile; 4 waves each own a K/4 chunk; LDS combine (fixed order);
// each wave epilogues its (i = wave>>1, j in {(wave&1)*2, +1}) slice.
// EPI: 0 Y=acc  5 Y+=relu(acc/denom[row])  7 Y=acc*maskf[row]+Y
template<int EPI, int TERMS>
__global__ __launch_bounds__(256)
void k_mfma3sk(const bf16* __restrict__ Ah, const bf16* __restrict__ Al,
               const bf16* __restrict__ Bh, const bf16* __restrict__ Bl,
               float* __restrict__ Y, const float* __restrict__ e0,
               const float* __restrict__ e1,
               int Kp, size_t sAb, size_t sBb)
{
  __shared__ float red[4][64][33];
  int b = blockIdx.z;
  int wave = threadIdx.x >> 6, lane = threadIdx.x & 63;
  int r0 = blockIdx.y*32;
  int c0 = blockIdx.x*64;
  int lm = lane & 15, lq = lane >> 4;
  size_t a0 = (size_t)b*sAb + (size_t)(r0+lm)*Kp + lq*8;
  size_t bo = (size_t)b*sBb + (size_t)(c0+lm)*Kp + lq*8;
  int kb = wave*(Kp>>2), ke = kb + (Kp>>2);

  f32x4 acc[2][4] = {};
  for (int k = kb; k < ke; k += 32){
    bf16x8 ah[2], bh[4], bl[4];
    #pragma unroll
    for (int i = 0; i < 2; i++) ah[i] = *(const bf16x8*)(Ah + a0 + (size_t)(i*16)*Kp + k);
    #pragma unroll
    for (int j = 0; j < 4; j++){
      bh[j] = *(const bf16x8*)(Bh + bo + (size_t)(j*16)*Kp + k);
      bl[j] = *(const bf16x8*)(Bl + bo + (size_t)(j*16)*Kp + k);
    }
    #pragma unroll
    for (int i = 0; i < 2; i++)
      #pragma unroll
      for (int j = 0; j < 4; j++) acc[i][j] = MFMA16(ah[i], bh[j], acc[i][j]);
    #pragma unroll
    for (int i = 0; i < 2; i++)
      #pragma unroll
      for (int j = 0; j < 4; j++) acc[i][j] = MFMA16(ah[i], bl[j], acc[i][j]);
    if (TERMS >= 3){
      bf16x8 al[2];
      #pragma unroll
      for (int i = 0; i < 2; i++) al[i] = *(const bf16x8*)(Al + a0 + (size_t)(i*16)*Kp + k);
      #pragma unroll
      for (int i = 0; i < 2; i++)
        #pragma unroll
        for (int j = 0; j < 4; j++) acc[i][j] = MFMA16(al[i], bh[j], acc[i][j]);
    }
  }

  #pragma unroll
  for (int i = 0; i < 2; i++)
    #pragma unroll
    for (int j = 0; j < 4; j++)
      #pragma unroll
      for (int r = 0; r < 4; r++)
        red[wave][lane][i*16 + j*4 + r] = acc[i][j][r];
  __syncthreads();

  int iw = wave >> 1, j0 = (wave & 1)*2;
  #pragma unroll
  for (int jj = 0; jj < 2; jj++){
    int j = j0 + jj;
    int col = c0 + j*16 + lm;
    #pragma unroll
    for (int r = 0; r < 4; r++){
      int f = iw*16 + j*4 + r;
      float v = red[0][lane][f] + red[1][lane][f] + red[2][lane][f] + red[3][lane][f];
      int row = r0 + iw*16 + lq*4 + r;
      size_t rowg = (size_t)b*Nd + row;
      if (EPI == 0){
        if (col < Hd) Y[rowg*Hd + col] = v;
      } else if (EPI == 5){
        if (col < Hd){
          float u = v / e0[b*Nd+row]; u = u > 0.f ? u : 0.f;
          Y[rowg*Hd + col] += u;
        }
      } else if (EPI == 7){
        if (col < Hd) Y[rowg*Hd+col] = v*e1[b*Nd+row] + Y[rowg*Hd+col];
      }
    }
  }
}

// ============================ fused softmax mix, split-K=4 ======================
// Y[b,n,d] = (sum_m exp(S[b,n,m]-rmax)/rsum * B[d,m]) [* maskf[b,n] + R[b,n,d]]
// A-frags built on the fly from fp32 S. PSINGLE=1: single-bf16 P (attention ctx);
// PSINGLE=0: Dekker-split P (alignment new_outs). EPI: 0 plain, 6 mask+R.
template<int EPI, int PSINGLE>
__global__ __launch_bounds__(256)
void k_mix(const float* __restrict__ S, const float* __restrict__ rmax,
           const float* __restrict__ rsum,
           const bf16* __restrict__ Bh, const bf16* __restrict__ Bl,
           float* __restrict__ Y, const float* __restrict__ maskf,
           const float* __restrict__ R)
{
  __shared__ float red[4][64][33];
  int b = blockIdx.z;
  int wave = threadIdx.x >> 6, lane = threadIdx.x & 63;
  int r0 = blockIdx.y*32;
  int c0 = blockIdx.x*64;
  int lm = lane & 15, lq = lane >> 4;
  const float* pS0 = S + (size_t)b*Nd*Nd + (size_t)(r0+lm)*Nd + lq*8;
  const float* pS1 = pS0 + (size_t)16*Nd;
  size_t bo = (size_t)b*((size_t)HP*Nd) + (size_t)(c0+lm)*Nd + lq*8;
  float rm0 = rmax[b*Nd + r0+lm],    ri0 = 1.f / rsum[b*Nd + r0+lm];
  float rm1 = rmax[b*Nd + r0+16+lm], ri1 = 1.f / rsum[b*Nd + r0+16+lm];
  int kb = wave*(Nd>>2), ke = kb + (Nd>>2);

  f32x4 acc[2][4] = {};
  for (int k = kb; k < ke; k += 32){
    bf16x8 ah[2], al[2], bh[4], bl[4];
    #pragma unroll
    for (int j = 0; j < 4; j++){
      bh[j] = *(const bf16x8*)(Bh + bo + (size_t)(j*16)*Nd + k);
      bl[j] = *(const bf16x8*)(Bl + bo + (size_t)(j*16)*Nd + k);
    }
    #pragma unroll
    for (int j = 0; j < 8; j++){
      float p0 = expf(pS0[k+j] - rm0) * ri0;
      bf16 h0 = f2bf(p0);
      ah[0][j] = bfbits(h0);
      float p1 = expf(pS1[k+j] - rm1) * ri1;
      bf16 h1 = f2bf(p1);
      ah[1][j] = bfbits(h1);
      if (!PSINGLE){
        al[0][j] = bfbits(f2bf(p0 - bf2f(h0)));
        al[1][j] = bfbits(f2bf(p1 - bf2f(h1)));
      }
    }
    #pragma unroll
    for (int i = 0; i < 2; i++)
      #pragma unroll
      for (int j = 0; j < 4; j++) acc[i][j] = MFMA16(ah[i], bh[j], acc[i][j]);
    #pragma unroll
    for (int i = 0; i < 2; i++)
      #pragma unroll
      for (int j = 0; j < 4; j++) acc[i][j] = MFMA16(ah[i], bl[j], acc[i][j]);
    if (!PSINGLE){
      #pragma unroll
      for (int i = 0; i < 2; i++)
        #pragma unroll
        for (int j = 0; j < 4; j++) acc[i][j] = MFMA16(al[i], bh[j], acc[i][j]);
    }
  }

  #pragma unroll
  for (int i = 0; i < 2; i++)
    #pragma unroll
    for (int j = 0; j < 4; j++)
      #pragma unroll
      for (int r = 0; r < 4; r++)
        red[wave][lane][i*16 + j*4 + r] = acc[i][j][r];
  __syncthreads();

  int iw = wave >> 1, j0 = (wave & 1)*2;
  #pragma unroll
  for (int jj = 0; jj < 2; jj++){
    int j = j0 + jj;
    int col = c0 + j*16 + lm;
    if (col >= Hd) continue;
    #pragma unroll
    for (int r = 0; r < 4; r++){
      int f = iw*16 + j*4 + r;
      float v = red[0][lane][f] + red[1][lane][f] + red[2][lane][f] + red[3][lane][f];
      int row = r0 + iw*16 + lq*4 + r;
      size_t rowg = (size_t)b*Nd + row;
      if (EPI == 0) Y[rowg*Hd + col] = v;
      else          Y[rowg*Hd + col] = v*maskf[b*Nd+row] + R[rowg*Hd + col];
    }
  }
}

// ============================ host launch ============================
static inline char* carve(char*& p, size_t bytes){
  char* r = p;
  p += (bytes + 511) & ~(size_t)511;
  return r;
}

extern "C" void kernel_launch(void* const* d_in, const int* in_sizes, int n_in,
                              void* d_out, int out_size, void* d_ws, size_t ws_size,
                              hipStream_t stream){
  (void)in_sizes; (void)n_in; (void)out_size; (void)ws_size;
  const float* text     = (const float*)d_in[0];
  const float* adj1     = (const float*)d_in[1];
  const float* adj2     = (const float*)d_in[2];
  const float* textmask = (const float*)d_in[5];
  const float* gcn_w    = (const float*)d_in[6];
  const float* mut_w    = (const float*)d_in[7];
  const float* qw = (const float*)d_in[8],  *qb = (const float*)d_in[9];
  const float* kw = (const float*)d_in[10], *kb = (const float*)d_in[11];
  const float* vw = (const float*)d_in[12], *vb = (const float*)d_in[13];
  const float* aow= (const float*)d_in[14], *aob= (const float*)d_in[15];
  const float* g1 = (const float*)d_in[16], *b1 = (const float*)d_in[17];
  const float* iw = (const float*)d_in[18], *ib = (const float*)d_in[19];
  const float* ow = (const float*)d_in[20], *ob = (const float*)d_in[21];
  const float* g2 = (const float*)d_in[22], *b2 = (const float*)d_in[23];

  float* out_outs = (float*)d_out;
  float* out_adj  = out_outs + SZ_BNH;

  // ---- workspace carve (~109 MB). out_outs doubles as fp32 scratch sc2. ----
  char* p = (char*)d_ws;
  float* cur  = (float*)carve(p, SZ_BNH*4);
  float* sc1  = (float*)carve(p, SZ_BNH*4);
  float* fo   = (float*)carve(p, SZ_BNH*4);
  float* S    = (float*)carve(p, SZ_BNN*4);           // fp32 scores / logits
  bf16*  Rb   = (bf16*)carve(p, SZ_BNN*2*2);          // big bf16 region (33.6 MB)
  bf16*  T1   = (bf16*)carve(p, SZ_PAD*2);
  bf16*  T2   = (bf16*)carve(p, SZ_PAD*2);
  bf16*  T3   = (bf16*)carve(p, SZ_PAD*2);
  bf16*  T4   = (bf16*)carve(p, SZ_PAD*2);
  bf16*  T5   = (bf16*)carve(p, SZ_PAD*2);
  bf16*  T6   = (bf16*)carve(p, SZ_PAD*2);
  bf16*  Wh   = (bf16*)carve(p, (size_t)HP*HP*2);
  bf16*  Wl   = (bf16*)carve(p, (size_t)HP*HP*2);
  float* denom   = (float*)carve(p, BN*4);
  float* maskf   = (float*)carve(p, BN*4);
  float* maskadd = (float*)carve(p, BN*4);
  float* rmaxv   = (float*)carve(p, BN*4);
  float* rsumv   = (float*)carve(p, BN*4);
  float* cmaxv   = (float*)carve(p, BN*4);
  float* csumv   = (float*)carve(p, BN*4);

  float* sc2 = out_outs;          // fp32 scratch; overwritten by final k_store
  bf16* adjb  = Rb;               // phases: adjb -> Ph/Pl (sequential)
  bf16* Ph    = Rb;
  bf16* Pl    = Rb + SZ_BNN;

  const size_t sNT = (size_t)Nd*HP;     // batch stride, [1024][224]
  const size_t sT  = (size_t)HP*Nd;     // batch stride, [224][1024]
  const size_t sNN = (size_t)Nd*Nd;     // batch stride, [1024][1024]

  dim3 blk256(256);
  dim3 gPad((unsigned)((SZ_PAD+255)/256));
  dim3 gPadT(32, 7, Bd), bT(32, 8);
  dim3 gPcolT(32, 32, Bd);
  dim3 gW((HP*HP+255)/256);
  dim3 gNNel((unsigned)((SZ_BNN+255)/256));
  dim3 gBNH((unsigned)((SZ_BNH+255)/256));
  // GEMM grids
  dim3 gSm(4, 128, 1);       // small GEMM: 16x64/wave, 8192 rows, K=HP
  dim3 gNT(16, 8, Bd);       // scores/logits: 32x64/wave, K=HP
  dim3 gSK(4, 32, Bd);       // split-K=4 mixes: one 32x64 tile per block, K=1024
  const float inv_sqrt_h = 0.07071067811865475f;  // 1/sqrt(200)
  const size_t Z = 0;

  k_prep_masks<<<(BN+255)/256, blk256, 0, stream>>>(textmask, maskf, maskadd);
  k_prep_adj<<<BN, blk256, 0, stream>>>(adj1, adj2, out_adj, denom);
  k_copy2<<<gBNH, blk256, 0, stream>>>(text, cur, fo);

  for (int i = 0; i < 3; i++){
    const float *qwi = qw + i*Hd*Hd, *qbi = qb + i*Hd;
    const float *kwi = kw + i*Hd*Hd, *kbi = kb + i*Hd;
    const float *vwi = vw + i*Hd*Hd, *vbi = vb + i*Hd;
    const float *aowi= aow+ i*Hd*Hd, *aobi= aob+ i*Hd;
    const float *g1i = g1 + i*Hd,    *b1i = b1 + i*Hd;
    const float *iwi = iw + i*Hd*Hd, *ibi = ib + i*Hd;
    const float *owi = ow + i*Hd*Hd, *obi = ob + i*Hd;
    const float *g2i = g2 + i*Hd,    *b2i = b2 + i*Hd;

    // ================= BERT layer: cur -> cur =================
    c_pad_split<<<gPad, blk256, 0, stream>>>(cur, T1, T2);                  // cur pair
    c_w_split<<<gW, blk256, 0, stream>>>(qwi, Wh, Wl);
    k_mfma3<2,3,1><<<gSm, blk256, 0, stream>>>(T1,T2,Wh,Wl, nullptr,T3,T4,
              qbi, nullptr,nullptr, HP, Z,Z, 0.f);                          // Q pair
    c_w_split<<<gW, blk256, 0, stream>>>(kwi, Wh, Wl);
    k_mfma3<2,3,1><<<gSm, blk256, 0, stream>>>(T1,T2,Wh,Wl, nullptr,T5,T6,
              kbi, nullptr,nullptr, HP, Z,Z, 0.f);                          // K pair
    k_mfma3<3,3,2><<<gNT, blk256, 0, stream>>>(T3,T4,T5,T6, S,nullptr,nullptr,
              nullptr, maskadd,nullptr, HP, sNT,sNT, inv_sqrt_h);           // scores
    c_w_split<<<gW, blk256, 0, stream>>>(vwi, Wh, Wl);
    k_mfma3<0,3,1><<<gSm, blk256, 0, stream>>>(T1,T2,Wh,Wl, sc1,nullptr,nullptr,
              vbi, nullptr,nullptr, HP, Z,Z, 0.f);                          // V fp32
    k_rowstats<<<BN, blk256, 0, stream>>>(S, rmaxv, rsumv);
    c_padT_split<<<gPadT, bT, 0, stream>>>(sc1, T1, T2);                    // V^T pair
    k_mix<0,1><<<gSK, blk256, 0, stream>>>(S, rmaxv, rsumv, T1, T2,
              sc2, nullptr, nullptr);                                       // ctx (fused exp)
    c_pad_split<<<gPad, blk256, 0, stream>>>(sc2, T3, T4);
    c_w_split<<<gW, blk256, 0, stream>>>(aowi, Wh, Wl);
    k_mfma3<0,3,1><<<gSm, blk256, 0, stream>>>(T3,T4,Wh,Wl, sc1,nullptr,nullptr,
              aobi, nullptr,nullptr, HP, Z,Z, 0.f);                         // ao_out
    k_add_ln<<<BN, blk256, 0, stream>>>(sc1, cur, g1i, b1i, sc2);           // attn -> sc2
    c_pad_split<<<gPad, blk256, 0, stream>>>(sc2, T1, T2);
    c_w_split<<<gW, blk256, 0, stream>>>(iwi, Wh, Wl);
    k_mfma3<1,3,1><<<gSm, blk256, 0, stream>>>(T1,T2,Wh,Wl, sc1,nullptr,nullptr,
              ibi, nullptr,nullptr, HP, Z,Z, 0.f);                          // gelu(inter)
    c_pad_split<<<gPad, blk256, 0, stream>>>(sc1, T3, T4);
    c_w_split<<<gW, blk256, 0, stream>>>(owi, Wh, Wl);
    k_mfma3<0,3,1><<<gSm, blk256, 0, stream>>>(T3,T4,Wh,Wl, cur,nullptr,nullptr,
              obi, nullptr,nullptr, HP, Z,Z, 0.f);                          // ow_out -> cur
    k_add_ln<<<BN, blk256, 0, stream>>>(cur, sc2, g2i, b2i, cur);           // bert out

    // ================= GCN on fo =================
    c_pad_split<<<gPad, blk256, 0, stream>>>(fo, T1, T2);
    c_w_split<<<gW, blk256, 0, stream>>>(gcn_w, Wh, Wl);
    k_mfma3<0,3,1><<<gSm, blk256, 0, stream>>>(T1,T2,Wh,Wl, sc1,nullptr,nullptr,
              nullptr, nullptr,nullptr, HP, Z,Z, 0.f);                      // teout
    c_padT_split<<<gPadT, bT, 0, stream>>>(sc1, T3, T4);                    // teout^T pair
    c_cvt1024<<<gNNel, blk256, 0, stream>>>(out_adj, adjb);                 // adj bf16 exact
    k_mfma3sk<5,2><<<gSK, blk256, 0, stream>>>(adjb,nullptr,T3,T4,
              fo, denom,nullptr, Nd, sNN,sT);                               // fo += relu(./denom)

    // ================= self-alignment =================
    c_pad_split<<<gPad, blk256, 0, stream>>>(cur, T1, T2);
    c_w_split<<<gW, blk256, 0, stream>>>(mut_w, Wh, Wl);
    k_mfma3<2,3,1><<<gSm, blk256, 0, stream>>>(T1,T2,Wh,Wl, nullptr,T5,T6,
              nullptr, nullptr,nullptr, HP, Z,Z, 0.f);                      // mm pair
    c_pad_split<<<gPad, blk256, 0, stream>>>(fo, T1, T2);                   // fo pad pair
    k_mfma3<4,3,2><<<gNT, blk256, 0, stream>>>(T5,T6,T1,T2, S,nullptr,nullptr,
              nullptr, nullptr,maskf, HP, sNT,sNT, 0.f);                    // logits -> S
    k_colstats<<<dim3(Nd/64, Bd), dim3(1024), 0, stream>>>(S, cmaxv, csumv);
    k_rowstats<<<BN, blk256, 0, stream>>>(S, rmaxv, rsumv);
    c_padT_split<<<gPadT, bT, 0, stream>>>(fo, T1, T2);                     // output^T pair
    k_mix<6,0><<<gSK, blk256, 0, stream>>>(S, rmaxv, rsumv, T1, T2,
              sc1, maskf, cur);                                             // new_outs -> sc1
    c_pcolT_split<<<gPcolT, bT, 0, stream>>>(S, cmaxv, csumv, Ph, Pl);      // p_col^T pair
    c_padT_split<<<gPadT, bT, 0, stream>>>(cur, T3, T4);                    // outs^T pair (old)
    k_mfma3sk<7,3><<<gSK, blk256, 0, stream>>>(Ph,Pl,T3,T4,
              fo, nullptr,maskf, Nd, sNN,sT);                               // fo update

    float* t = cur; cur = sc1; sc1 = t;   // outs = new_outs
  }

  k_store<<<gBNH, blk256, 0, stream>>>(cur, out_outs);
}